// Round 1
// baseline (5801.255 us; speedup 1.0000x reference)
//
#include <hip/hip_runtime.h>
#include <hip/hip_bf16.h>

#define DD 128
#define TM 64

// ---------------------------------------------------------------------------
// degree: cnt[dst[e]] += 1
__global__ __launch_bounds__(256) void degree_kernel(
    const int* __restrict__ dst, float* __restrict__ cnt, int nE)
{
    int e = blockIdx.x * 256 + threadIdx.x;
    if (e < nE) unsafeAtomicAdd(&cnt[dst[e]], 1.0f);
}

// cnt -> 1/max(cnt,1)  (in place)
__global__ __launch_bounds__(256) void inv_kernel(float* __restrict__ c, int n)
{
    int i = blockIdx.x * 256 + threadIdx.x;
    if (i < n) c[i] = 1.0f / fmaxf(c[i], 1.0f);
}

// ---------------------------------------------------------------------------
// scatter: S[dst[e]] += X[src[e]]   (32 lanes per edge, float4 per lane)
__global__ __launch_bounds__(256) void scatter_kernel(
    const float* __restrict__ X, const int* __restrict__ src,
    const int* __restrict__ dst, float* __restrict__ S, int nE)
{
    int e = (blockIdx.x * 256 + threadIdx.x) >> 5;
    int l = threadIdx.x & 31;
    if (e >= nE) return;
    int s = src[e];
    int d = dst[e];
    float4 v = *(const float4*)(X + (size_t)s * DD + l * 4);
    float* p = S + (size_t)d * DD + l * 4;
    unsafeAtomicAdd(p + 0, v.x);
    unsafeAtomicAdd(p + 1, v.y);
    unsafeAtomicAdd(p + 2, v.z);
    unsafeAtomicAdd(p + 3, v.w);
}

// ---------------------------------------------------------------------------
// Y[i] = (S[i]*inv[i]) @ Wl + bl + X[i] @ Wr     (unnormalized)
// X may alias Y (in-place per-row: rows loaded to LDS before any store).
__global__ __launch_bounds__(256) void mm_kernel(
    const float* __restrict__ S, const float* __restrict__ Inv,
    const float* X,
    const float* __restrict__ Wl, const float* __restrict__ Wr,
    const float* __restrict__ bl,
    float* Y, int n)
{
    __shared__ float A1[TM][DD + 1];
    __shared__ float A2[TM][DD + 1];
    const int tid  = threadIdx.x;
    const int row0 = blockIdx.x * TM;

    // ---- load 64 rows of agg (=S*inv) and X into LDS -----------------------
    {
        int c4 = (tid & 31) * 4;
        int rb = tid >> 5;              // 0..7
        #pragma unroll
        for (int i = 0; i < 8; ++i) {
            int r = rb * 8 + i;
            int g = row0 + r;
            float4 v1 = make_float4(0.f, 0.f, 0.f, 0.f);
            float4 v2 = v1;
            if (g < n) {
                v1 = *(const float4*)(S + (size_t)g * DD + c4);
                float iv = Inv[g];
                v1.x *= iv; v1.y *= iv; v1.z *= iv; v1.w *= iv;
                v2 = *(const float4*)(X + (size_t)g * DD + c4);
            }
            A1[r][c4 + 0] = v1.x; A1[r][c4 + 1] = v1.y;
            A1[r][c4 + 2] = v1.z; A1[r][c4 + 3] = v1.w;
            A2[r][c4 + 0] = v2.x; A2[r][c4 + 1] = v2.y;
            A2[r][c4 + 2] = v2.z; A2[r][c4 + 3] = v2.w;
        }
    }
    __syncthreads();

    // ---- register tile: 4 rows x 8 cols per thread --------------------------
    const int cg = tid & 15;            // col group -> coalesced W reads/stores
    const int rg = tid >> 4;            // row group -> broadcast LDS reads
    const int c0 = cg * 8;
    const int r0 = rg * 4;

    float acc[4][8];
    #pragma unroll
    for (int r = 0; r < 4; ++r)
        #pragma unroll
        for (int c = 0; c < 8; ++c) acc[r][c] = 0.f;

    const float* wlp = Wl + c0;
    const float* wrp = Wr + c0;

    #pragma unroll 2
    for (int k = 0; k < DD; ++k) {
        float4 w1a = *(const float4*)(wlp + k * DD);
        float4 w1b = *(const float4*)(wlp + k * DD + 4);
        float4 w2a = *(const float4*)(wrp + k * DD);
        float4 w2b = *(const float4*)(wrp + k * DD + 4);
        float a1[4], a2[4];
        #pragma unroll
        for (int r = 0; r < 4; ++r) {
            a1[r] = A1[r0 + r][k];
            a2[r] = A2[r0 + r][k];
        }
        #pragma unroll
        for (int r = 0; r < 4; ++r) {
            acc[r][0] += a1[r] * w1a.x + a2[r] * w2a.x;
            acc[r][1] += a1[r] * w1a.y + a2[r] * w2a.y;
            acc[r][2] += a1[r] * w1a.z + a2[r] * w2a.z;
            acc[r][3] += a1[r] * w1a.w + a2[r] * w2a.w;
            acc[r][4] += a1[r] * w1b.x + a2[r] * w2b.x;
            acc[r][5] += a1[r] * w1b.y + a2[r] * w2b.y;
            acc[r][6] += a1[r] * w1b.z + a2[r] * w2b.z;
            acc[r][7] += a1[r] * w1b.w + a2[r] * w2b.w;
        }
    }

    // ---- bias + store --------------------------------------------------------
    float4 b0 = *(const float4*)(bl + c0);
    float4 b1 = *(const float4*)(bl + c0 + 4);
    #pragma unroll
    for (int r = 0; r < 4; ++r) {
        int g = row0 + r0 + r;
        if (g < n) {
            float4 o0 = make_float4(acc[r][0] + b0.x, acc[r][1] + b0.y,
                                    acc[r][2] + b0.z, acc[r][3] + b0.w);
            float4 o1 = make_float4(acc[r][4] + b1.x, acc[r][5] + b1.y,
                                    acc[r][6] + b1.z, acc[r][7] + b1.w);
            *(float4*)(Y + (size_t)g * DD + c0)     = o0;
            *(float4*)(Y + (size_t)g * DD + c0 + 4) = o1;
        }
    }
}

// ---------------------------------------------------------------------------
// per-row L2 normalize + ReLU, in place. One wave per row.
__global__ __launch_bounds__(256) void norm_relu_kernel(float* __restrict__ Y, int n)
{
    int row  = (blockIdx.x * 256 + threadIdx.x) >> 6;
    int lane = threadIdx.x & 63;
    if (row >= n) return;
    float* p = Y + (size_t)row * DD + lane * 2;
    float2 v = *(float2*)p;
    float ss = v.x * v.x + v.y * v.y;
    #pragma unroll
    for (int off = 32; off; off >>= 1) ss += __shfl_xor(ss, off);
    float sc = 1.0f / fmaxf(sqrtf(ss), 1e-12f);
    v.x = fmaxf(v.x * sc, 0.0f);
    v.y = fmaxf(v.y * sc, 0.0f);
    *(float2*)p = v;
}

// ---------------------------------------------------------------------------
extern "C" void kernel_launch(void* const* d_in, const int* in_sizes, int n_in,
                              void* d_out, int out_size, void* d_ws, size_t ws_size,
                              hipStream_t stream)
{
    const float* x   = (const float*)d_in[0];
    const int*   ei  = (const int*)d_in[1];
    const float* Wl1 = (const float*)d_in[2];
    const float* bl1 = (const float*)d_in[3];
    const float* Wr1 = (const float*)d_in[4];
    const float* Wl2 = (const float*)d_in[5];
    const float* bl2 = (const float*)d_in[6];
    const float* Wr2 = (const float*)d_in[7];
    float* out = (float*)d_out;

    const int N = in_sizes[0] / DD;
    const int E = in_sizes[1] / 2;
    const int* src = ei;
    const int* dst = ei + E;

    float* S   = (float*)d_ws;                 // [N][128] aggregation sums
    float* Cnt = S + (size_t)N * DD;           // [N] degree -> inv

    const size_t sbytes = (size_t)N * DD * sizeof(float);

    // degree (once; graph identical for both layers)
    hipMemsetAsync(Cnt, 0, (size_t)N * sizeof(float), stream);
    degree_kernel<<<(E + 255) / 256, 256, 0, stream>>>(dst, Cnt, E);
    inv_kernel<<<(N + 255) / 256, 256, 0, stream>>>(Cnt, N);

    // ---- layer 1: h1 (in d_out) = relu(normalize(agg(x)@Wl1 + bl1 + x@Wr1))
    hipMemsetAsync(S, 0, sbytes, stream);
    scatter_kernel<<<(E + 7) / 8, 256, 0, stream>>>(x, src, dst, S, E);
    mm_kernel<<<(N + TM - 1) / TM, 256, 0, stream>>>(S, Cnt, x, Wl1, Wr1, bl1, out, N);
    norm_relu_kernel<<<(N + 3) / 4, 256, 0, stream>>>(out, N);

    // ---- layer 2: out = relu(normalize(agg(h1)@Wl2 + bl2 + h1@Wr2))  (in place)
    hipMemsetAsync(S, 0, sbytes, stream);
    scatter_kernel<<<(E + 7) / 8, 256, 0, stream>>>(out, src, dst, S, E);
    mm_kernel<<<(N + TM - 1) / TM, 256, 0, stream>>>(S, Cnt, out, Wl2, Wr2, bl2, out, N);
    norm_relu_kernel<<<(N + 3) / 4, 256, 0, stream>>>(out, N);
}

// Round 2
// 749.227 us; speedup vs baseline: 7.7430x; 7.7430x over previous
//
#include <hip/hip_runtime.h>
#include <hip/hip_bf16.h>

#define DD 128
#define TM 64

// ===========================================================================
// CSR construction
// ===========================================================================

// deg[dst[e]] += 1  (int atomics on 400 KB -- fast)
__global__ __launch_bounds__(256) void deg_kernel(
    const int* __restrict__ dst, int* __restrict__ deg, int nE)
{
    int e = blockIdx.x * 256 + threadIdx.x;
    if (e < nE) atomicAdd(&deg[dst[e]], 1);
}

// block-local inclusive scan (256 elems/block) + per-block totals
__global__ __launch_bounds__(256) void scan1_kernel(
    const int* __restrict__ deg, int* __restrict__ inc,
    int* __restrict__ bsum, int n)
{
    __shared__ int tmp[256];
    int i = blockIdx.x * 256 + threadIdx.x;
    int t = threadIdx.x;
    tmp[t] = (i < n) ? deg[i] : 0;
    __syncthreads();
    for (int off = 1; off < 256; off <<= 1) {
        int v = (t >= off) ? tmp[t - off] : 0;
        __syncthreads();
        tmp[t] += v;
        __syncthreads();
    }
    if (i < n) inc[i] = tmp[t];
    if (t == 255) bsum[blockIdx.x] = tmp[255];
}

// single-block exclusive scan of the block totals (nb <= 512)
__global__ __launch_bounds__(512) void scan2_kernel(int* __restrict__ bsum, int nb)
{
    __shared__ int tmp[512];
    int t = threadIdx.x;
    tmp[t] = (t < nb) ? bsum[t] : 0;
    __syncthreads();
    for (int off = 1; off < 512; off <<= 1) {
        int v = (t >= off) ? tmp[t - off] : 0;
        __syncthreads();
        tmp[t] += v;
        __syncthreads();
    }
    if (t < nb) bsum[t] = (t == 0) ? 0 : tmp[t - 1];
}

// rowptr / cursor / inv-degree from scan pieces
__global__ __launch_bounds__(256) void scan3_kernel(
    const int* __restrict__ inc, const int* __restrict__ bsum,
    const int* __restrict__ deg, int* __restrict__ rowptr,
    int* __restrict__ cursor, float* __restrict__ invd, int n)
{
    int i = blockIdx.x * 256 + threadIdx.x;
    if (i > n) return;
    int rp = (i == 0) ? 0 : (inc[i - 1] + bsum[(i - 1) >> 8]);
    rowptr[i] = rp;
    if (i < n) {
        cursor[i] = rp;
        invd[i]   = 1.0f / fmaxf((float)deg[i], 1.0f);
    }
}

// csr[cursor[dst[e]]++] = src[e]
__global__ __launch_bounds__(256) void fill_kernel(
    const int* __restrict__ src, const int* __restrict__ dst,
    int* __restrict__ cursor, int* __restrict__ csr, int nE)
{
    int e = blockIdx.x * 256 + threadIdx.x;
    if (e < nE) {
        int pos = atomicAdd(&cursor[dst[e]], 1);
        csr[pos] = src[e];
    }
}

// ===========================================================================
// gather-aggregate: S[i] = mean over neighbors of X[csr[j]]  (pre-scaled)
// 16 lanes per node, 8 floats (2x float4) per lane.
// ===========================================================================
__global__ __launch_bounds__(256) void agg_kernel(
    const float* __restrict__ X, const int* __restrict__ csr,
    const int* __restrict__ rowptr, const float* __restrict__ invd,
    float* __restrict__ S, int n)
{
    int node = (blockIdx.x * 256 + threadIdx.x) >> 4;
    int l    = threadIdx.x & 15;
    if (node >= n) return;
    int beg = rowptr[node], end = rowptr[node + 1];
    float4 a0 = make_float4(0.f, 0.f, 0.f, 0.f);
    float4 a1 = a0;
    for (int j = beg; j < end; ++j) {
        const float* p = X + (size_t)csr[j] * DD + l * 8;
        float4 v0 = *(const float4*)p;
        float4 v1 = *(const float4*)(p + 4);
        a0.x += v0.x; a0.y += v0.y; a0.z += v0.z; a0.w += v0.w;
        a1.x += v1.x; a1.y += v1.y; a1.z += v1.z; a1.w += v1.w;
    }
    float iv = invd[node];
    a0.x *= iv; a0.y *= iv; a0.z *= iv; a0.w *= iv;
    a1.x *= iv; a1.y *= iv; a1.z *= iv; a1.w *= iv;
    float* q = S + (size_t)node * DD + l * 8;
    *(float4*)q       = a0;
    *(float4*)(q + 4) = a1;
}

// ===========================================================================
// fallback pieces (atomic scatter path) if ws is too small for CSR
// ===========================================================================
__global__ __launch_bounds__(256) void degree_f_kernel(
    const int* __restrict__ dst, float* __restrict__ cnt, int nE)
{
    int e = blockIdx.x * 256 + threadIdx.x;
    if (e < nE) unsafeAtomicAdd(&cnt[dst[e]], 1.0f);
}

__global__ __launch_bounds__(256) void inv_kernel(float* __restrict__ c, int n)
{
    int i = blockIdx.x * 256 + threadIdx.x;
    if (i < n) c[i] = 1.0f / fmaxf(c[i], 1.0f);
}

__global__ __launch_bounds__(256) void scatter_kernel(
    const float* __restrict__ X, const int* __restrict__ src,
    const int* __restrict__ dst, float* __restrict__ S, int nE)
{
    int e = (blockIdx.x * 256 + threadIdx.x) >> 5;
    int l = threadIdx.x & 31;
    if (e >= nE) return;
    int s = src[e];
    int d = dst[e];
    float4 v = *(const float4*)(X + (size_t)s * DD + l * 4);
    float* p = S + (size_t)d * DD + l * 4;
    unsafeAtomicAdd(p + 0, v.x);
    unsafeAtomicAdd(p + 1, v.y);
    unsafeAtomicAdd(p + 2, v.z);
    unsafeAtomicAdd(p + 3, v.w);
}

// S[row] *= inv[row]  (one float4 per thread)
__global__ __launch_bounds__(256) void scale_kernel(
    float* __restrict__ S, const float* __restrict__ invd, int n)
{
    int i = blockIdx.x * 256 + threadIdx.x;     // float4 index
    if (i >= n * (DD / 4)) return;
    int row = i / (DD / 4);
    float iv = invd[row];
    float4* p = (float4*)S + i;
    float4 v = *p;
    v.x *= iv; v.y *= iv; v.z *= iv; v.w *= iv;
    *p = v;
}

// ===========================================================================
// Y[i] = normalize_relu( S[i] @ Wl + bl + X[i] @ Wr )
// S is the PRE-SCALED mean aggregate. X may alias Y (rows staged to LDS).
// Fused per-row L2 normalize + ReLU in the epilogue.
// ===========================================================================
__global__ __launch_bounds__(256) void mm_kernel(
    const float* __restrict__ S, const float* X,
    const float* __restrict__ Wl, const float* __restrict__ Wr,
    const float* __restrict__ bl,
    float* Y, int n)
{
    __shared__ float A1[TM][DD + 1];
    __shared__ float A2[TM][DD + 1];
    const int tid  = threadIdx.x;
    const int row0 = blockIdx.x * TM;

    // ---- stage 64 rows of S and X into LDS ---------------------------------
    {
        int c4 = (tid & 31) * 4;
        int rb = tid >> 5;              // 0..7
        #pragma unroll
        for (int i = 0; i < 8; ++i) {
            int r = rb * 8 + i;
            int g = row0 + r;
            float4 v1 = make_float4(0.f, 0.f, 0.f, 0.f);
            float4 v2 = v1;
            if (g < n) {
                v1 = *(const float4*)(S + (size_t)g * DD + c4);
                v2 = *(const float4*)(X + (size_t)g * DD + c4);
            }
            A1[r][c4 + 0] = v1.x; A1[r][c4 + 1] = v1.y;
            A1[r][c4 + 2] = v1.z; A1[r][c4 + 3] = v1.w;
            A2[r][c4 + 0] = v2.x; A2[r][c4 + 1] = v2.y;
            A2[r][c4 + 2] = v2.z; A2[r][c4 + 3] = v2.w;
        }
    }
    __syncthreads();

    // ---- register tile: 4 rows x 8 cols per thread -------------------------
    const int cg = tid & 15;            // col group (16 threads cover a row)
    const int rg = tid >> 4;            // row group
    const int c0 = cg * 8;
    const int r0 = rg * 4;

    float acc[4][8];
    #pragma unroll
    for (int r = 0; r < 4; ++r)
        #pragma unroll
        for (int c = 0; c < 8; ++c) acc[r][c] = 0.f;

    const float* wlp = Wl + c0;
    const float* wrp = Wr + c0;

    #pragma unroll 2
    for (int k = 0; k < DD; ++k) {
        float4 w1a = *(const float4*)(wlp + k * DD);
        float4 w1b = *(const float4*)(wlp + k * DD + 4);
        float4 w2a = *(const float4*)(wrp + k * DD);
        float4 w2b = *(const float4*)(wrp + k * DD + 4);
        float a1[4], a2[4];
        #pragma unroll
        for (int r = 0; r < 4; ++r) {
            a1[r] = A1[r0 + r][k];
            a2[r] = A2[r0 + r][k];
        }
        #pragma unroll
        for (int r = 0; r < 4; ++r) {
            acc[r][0] += a1[r] * w1a.x + a2[r] * w2a.x;
            acc[r][1] += a1[r] * w1a.y + a2[r] * w2a.y;
            acc[r][2] += a1[r] * w1a.z + a2[r] * w2a.z;
            acc[r][3] += a1[r] * w1a.w + a2[r] * w2a.w;
            acc[r][4] += a1[r] * w1b.x + a2[r] * w2b.x;
            acc[r][5] += a1[r] * w1b.y + a2[r] * w2b.y;
            acc[r][6] += a1[r] * w1b.z + a2[r] * w2b.z;
            acc[r][7] += a1[r] * w1b.w + a2[r] * w2b.w;
        }
    }

    // ---- bias, fused L2-normalize + ReLU, store ----------------------------
    float4 b0 = *(const float4*)(bl + c0);
    float4 b1 = *(const float4*)(bl + c0 + 4);
    #pragma unroll
    for (int r = 0; r < 4; ++r) {
        acc[r][0] += b0.x; acc[r][1] += b0.y; acc[r][2] += b0.z; acc[r][3] += b0.w;
        acc[r][4] += b1.x; acc[r][5] += b1.y; acc[r][6] += b1.z; acc[r][7] += b1.w;

        float ss = 0.f;
        #pragma unroll
        for (int c = 0; c < 8; ++c) ss += acc[r][c] * acc[r][c];
        // reduce across the 16 contiguous lanes of this row group
        ss += __shfl_xor(ss, 1);
        ss += __shfl_xor(ss, 2);
        ss += __shfl_xor(ss, 4);
        ss += __shfl_xor(ss, 8);
        float sc = 1.0f / fmaxf(sqrtf(ss), 1e-12f);

        int g = row0 + r0 + r;
        if (g < n) {
            float4 o0 = make_float4(fmaxf(acc[r][0] * sc, 0.f), fmaxf(acc[r][1] * sc, 0.f),
                                    fmaxf(acc[r][2] * sc, 0.f), fmaxf(acc[r][3] * sc, 0.f));
            float4 o1 = make_float4(fmaxf(acc[r][4] * sc, 0.f), fmaxf(acc[r][5] * sc, 0.f),
                                    fmaxf(acc[r][6] * sc, 0.f), fmaxf(acc[r][7] * sc, 0.f));
            *(float4*)(Y + (size_t)g * DD + c0)     = o0;
            *(float4*)(Y + (size_t)g * DD + c0 + 4) = o1;
        }
    }
}

// ===========================================================================
extern "C" void kernel_launch(void* const* d_in, const int* in_sizes, int n_in,
                              void* d_out, int out_size, void* d_ws, size_t ws_size,
                              hipStream_t stream)
{
    const float* x   = (const float*)d_in[0];
    const int*   ei  = (const int*)d_in[1];
    const float* Wl1 = (const float*)d_in[2];
    const float* bl1 = (const float*)d_in[3];
    const float* Wr1 = (const float*)d_in[4];
    const float* Wl2 = (const float*)d_in[5];
    const float* bl2 = (const float*)d_in[6];
    const float* Wr2 = (const float*)d_in[7];
    float* out = (float*)d_out;

    const int N = in_sizes[0] / DD;
    const int E = in_sizes[1] / 2;
    const int* src = ei;
    const int* dst = ei + E;

    // ---- workspace layout --------------------------------------------------
    char* w = (char*)d_ws;
    size_t off = 0;
    auto alloc = [&](size_t bytes) {
        void* p = w + off;
        off += (bytes + 255) & ~(size_t)255;
        return p;
    };
    float* S      = (float*)alloc((size_t)N * DD * sizeof(float));
    int*   csr    = (int*)  alloc((size_t)E * sizeof(int));
    int*   deg    = (int*)  alloc((size_t)N * sizeof(int));
    int*   inc    = (int*)  alloc((size_t)N * sizeof(int));
    int*   rowptr = (int*)  alloc((size_t)(N + 1) * sizeof(int));
    int*   cursor = (int*)  alloc((size_t)N * sizeof(int));
    float* invd   = (float*)alloc((size_t)N * sizeof(float));
    int*   bsum   = (int*)  alloc(512 * sizeof(int));
    const bool fast = (off <= ws_size);

    const int nb = (N + 255) / 256;         // scan blocks (must be <= 512)

    if (fast && nb <= 512) {
        // ---- build CSR (once; graph identical for both layers) -------------
        hipMemsetAsync(deg, 0, (size_t)N * sizeof(int), stream);
        deg_kernel  <<<(E + 255) / 256, 256, 0, stream>>>(dst, deg, E);
        scan1_kernel<<<nb, 256, 0, stream>>>(deg, inc, bsum, N);
        scan2_kernel<<<1, 512, 0, stream>>>(bsum, nb);
        scan3_kernel<<<(N + 256) / 256, 256, 0, stream>>>(inc, bsum, deg,
                                                          rowptr, cursor, invd, N);
        fill_kernel <<<(E + 255) / 256, 256, 0, stream>>>(src, dst, cursor, csr, E);

        const int aggGrid = (N * 16 + 255) / 256;
        // ---- layer 1 --------------------------------------------------------
        agg_kernel<<<aggGrid, 256, 0, stream>>>(x, csr, rowptr, invd, S, N);
        mm_kernel <<<(N + TM - 1) / TM, 256, 0, stream>>>(S, x, Wl1, Wr1, bl1, out, N);
        // ---- layer 2 (in place: agg reads out before mm rewrites it) -------
        agg_kernel<<<aggGrid, 256, 0, stream>>>(out, csr, rowptr, invd, S, N);
        mm_kernel <<<(N + TM - 1) / TM, 256, 0, stream>>>(S, out, Wl2, Wr2, bl2, out, N);
    } else {
        // ---- fallback: atomic scatter path (round-1 style) ------------------
        float* Cnt = S + (size_t)N * DD;
        const size_t sbytes = (size_t)N * DD * sizeof(float);

        hipMemsetAsync(Cnt, 0, (size_t)N * sizeof(float), stream);
        degree_f_kernel<<<(E + 255) / 256, 256, 0, stream>>>(dst, Cnt, E);
        inv_kernel<<<(N + 255) / 256, 256, 0, stream>>>(Cnt, N);

        hipMemsetAsync(S, 0, sbytes, stream);
        scatter_kernel<<<(E + 7) / 8, 256, 0, stream>>>(x, src, dst, S, E);
        scale_kernel<<<(N * 32 + 255) / 256, 256, 0, stream>>>(S, Cnt, N);
        mm_kernel<<<(N + TM - 1) / TM, 256, 0, stream>>>(S, x, Wl1, Wr1, bl1, out, N);

        hipMemsetAsync(S, 0, sbytes, stream);
        scatter_kernel<<<(E + 7) / 8, 256, 0, stream>>>(out, src, dst, S, E);
        scale_kernel<<<(N * 32 + 255) / 256, 256, 0, stream>>>(S, Cnt, N);
        mm_kernel<<<(N + TM - 1) / TM, 256, 0, stream>>>(S, out, Wl2, Wr2, bl2, out, N);
    }
}

// Round 3
// 418.039 us; speedup vs baseline: 13.8773x; 1.7922x over previous
//
#include <hip/hip_runtime.h>

#define DD 128

typedef short bf16x8 __attribute__((ext_vector_type(8)));
typedef float f32x4  __attribute__((ext_vector_type(4)));

// ---- bf16 helpers (RNE) ----------------------------------------------------
static __device__ __forceinline__ unsigned short f2b(float f) {
    union { float f; unsigned u; } v; v.f = f;
    unsigned u = v.u;
    return (unsigned short)((u + 0x7FFFu + ((u >> 16) & 1u)) >> 16);
}
static __device__ __forceinline__ float blo(unsigned p) {   // low bf16 of packed pair
    union { unsigned u; float f; } v; v.u = p << 16; return v.f;
}
static __device__ __forceinline__ float bhi(unsigned p) {   // high bf16 of packed pair
    union { unsigned u; float f; } v; v.u = p & 0xFFFF0000u; return v.f;
}

// ===========================================================================
// x (fp32) -> xb (bf16), 8 elems/thread
// ===========================================================================
__global__ __launch_bounds__(256) void cvt_kernel(
    const float* __restrict__ X, unsigned short* __restrict__ Xb, int n8)
{
    int i = blockIdx.x * 256 + threadIdx.x;
    if (i >= n8) return;
    const float4* p = (const float4*)(X + (size_t)i * 8);
    float4 a = p[0], b = p[1];
    uint4 o;
    o.x = f2b(a.x) | ((unsigned)f2b(a.y) << 16);
    o.y = f2b(a.z) | ((unsigned)f2b(a.w) << 16);
    o.z = f2b(b.x) | ((unsigned)f2b(b.y) << 16);
    o.w = f2b(b.z) | ((unsigned)f2b(b.w) << 16);
    *(uint4*)(Xb + (size_t)i * 8) = o;
}

// ===========================================================================
// CSR construction
// ===========================================================================
__global__ __launch_bounds__(256) void deg_kernel(
    const int* __restrict__ dst, int* __restrict__ deg, int nE)
{
    int e = blockIdx.x * 256 + threadIdx.x;
    if (e < nE) atomicAdd(&deg[dst[e]], 1);
}

__global__ __launch_bounds__(256) void scan1_kernel(
    const int* __restrict__ deg, int* __restrict__ inc,
    int* __restrict__ bsum, int n)
{
    __shared__ int tmp[256];
    int i = blockIdx.x * 256 + threadIdx.x;
    int t = threadIdx.x;
    tmp[t] = (i < n) ? deg[i] : 0;
    __syncthreads();
    for (int off = 1; off < 256; off <<= 1) {
        int v = (t >= off) ? tmp[t - off] : 0;
        __syncthreads();
        tmp[t] += v;
        __syncthreads();
    }
    if (i < n) inc[i] = tmp[t];
    if (t == 255) bsum[blockIdx.x] = tmp[255];
}

__global__ __launch_bounds__(512) void scan2_kernel(int* __restrict__ bsum, int nb)
{
    __shared__ int tmp[512];
    int t = threadIdx.x;
    tmp[t] = (t < nb) ? bsum[t] : 0;
    __syncthreads();
    for (int off = 1; off < 512; off <<= 1) {
        int v = (t >= off) ? tmp[t - off] : 0;
        __syncthreads();
        tmp[t] += v;
        __syncthreads();
    }
    if (t < nb) bsum[t] = (t == 0) ? 0 : tmp[t - 1];
}

__global__ __launch_bounds__(256) void scan3_kernel(
    const int* __restrict__ inc, const int* __restrict__ bsum,
    const int* __restrict__ deg, int* __restrict__ rowptr,
    int* __restrict__ cursor, float* __restrict__ invd, int n)
{
    int i = blockIdx.x * 256 + threadIdx.x;
    if (i > n) return;
    int rp = (i == 0) ? 0 : (inc[i - 1] + bsum[(i - 1) >> 8]);
    rowptr[i] = rp;
    if (i < n) {
        cursor[i] = rp;
        invd[i]   = 1.0f / fmaxf((float)deg[i], 1.0f);
    }
}

__global__ __launch_bounds__(256) void fill_kernel(
    const int* __restrict__ src, const int* __restrict__ dst,
    int* __restrict__ cursor, int* __restrict__ csr, int nE)
{
    int e = blockIdx.x * 256 + threadIdx.x;
    if (e < nE) {
        int pos = atomicAdd(&cursor[dst[e]], 1);
        csr[pos] = src[e];
    }
}

// ===========================================================================
// W permute: Wp[kk(8)][nt(8)][lane(64)][j(8)] = bf16(Wcat[k][c])
//   k = kk*32 + (lane>>4)*8 + j  (k<128 -> Wl, else Wr),  c = nt*16 + (lane&15)
// ===========================================================================
__global__ __launch_bounds__(256) void wprep_kernel(
    const float* __restrict__ Wl, const float* __restrict__ Wr,
    unsigned short* __restrict__ Wp)
{
    int t = blockIdx.x * 256 + threadIdx.x;      // 4096 total
    if (t >= 4096) return;
    int l  = t & 63;
    int nt = (t >> 6) & 7;
    int kk = t >> 9;
    int c  = nt * 16 + (l & 15);
    int k0 = kk * 32 + (l >> 4) * 8;
    unsigned short o[8];
    #pragma unroll
    for (int j = 0; j < 8; ++j) {
        int k = k0 + j;
        float v = (k < 128) ? Wl[k * 128 + c] : Wr[(k - 128) * 128 + c];
        o[j] = f2b(v);
    }
    uint4 pk;
    pk.x = o[0] | ((unsigned)o[1] << 16);
    pk.y = o[2] | ((unsigned)o[3] << 16);
    pk.z = o[4] | ((unsigned)o[5] << 16);
    pk.w = o[6] | ((unsigned)o[7] << 16);
    *(uint4*)(Wp + (size_t)t * 8) = pk;
}

// ===========================================================================
// gather-aggregate (bf16): Sb[i] = bf16( mean_j Xb[csr[j]] )
// 16 lanes/node, 16B (8 bf16) per lane, fp32 accumulate.
// ===========================================================================
__global__ __launch_bounds__(256) void aggb_kernel(
    const unsigned short* __restrict__ Xb, const int* __restrict__ csr,
    const int* __restrict__ rowptr, const float* __restrict__ invd,
    unsigned short* __restrict__ Sb, int n)
{
    int node = (blockIdx.x * 256 + threadIdx.x) >> 4;
    int l    = threadIdx.x & 15;
    if (node >= n) return;
    int beg = rowptr[node], end = rowptr[node + 1];
    float a0 = 0.f, a1 = 0.f, a2 = 0.f, a3 = 0.f;
    float a4 = 0.f, a5 = 0.f, a6 = 0.f, a7 = 0.f;
    for (int j = beg; j < end; ++j) {
        uint4 v = *(const uint4*)(Xb + (size_t)csr[j] * DD + l * 8);
        a0 += blo(v.x); a1 += bhi(v.x);
        a2 += blo(v.y); a3 += bhi(v.y);
        a4 += blo(v.z); a5 += bhi(v.z);
        a6 += blo(v.w); a7 += bhi(v.w);
    }
    float iv = invd[node];
    uint4 o;
    o.x = f2b(a0 * iv) | ((unsigned)f2b(a1 * iv) << 16);
    o.y = f2b(a2 * iv) | ((unsigned)f2b(a3 * iv) << 16);
    o.z = f2b(a4 * iv) | ((unsigned)f2b(a5 * iv) << 16);
    o.w = f2b(a6 * iv) | ((unsigned)f2b(a7 * iv) << 16);
    *(uint4*)(Sb + (size_t)node * DD + l * 8) = o;
}

// ===========================================================================
// MFMA GEMM + fused bias / L2-normalize / ReLU.
//   Y[i] = norm_relu( Sb[i] @ Wl + bl + Xb[i] @ Wr )   via [Sb|Xb] @ Wp
// 4 waves/block, each wave: 16 rows x 128 cols, 8 k-tiles x 8 n-tiles.
// Hb (bf16 out copy) MAY ALIAS Xb (per-row in-place: A-loads precede stores).
// ===========================================================================
__global__ __launch_bounds__(256) void mmf_kernel(
    const unsigned short* __restrict__ Sb,
    const unsigned short* Xb,            // no __restrict__: may alias Hb
    const unsigned short* __restrict__ Wp,
    const float* __restrict__ bl,
    float* __restrict__ Y,
    unsigned short* Hb,
    int n, int writeH)
{
    const int wid  = threadIdx.x >> 6;
    const int l    = threadIdx.x & 63;
    const int row0 = blockIdx.x * 64 + wid * 16;
    const int lr   = l & 15;             // A-row in tile / C-col in tile
    const int lk   = l >> 4;             // k-chunk (0..3)

    int arow = row0 + lr;
    if (arow >= n) arow = n - 1;         // clamp loads; stores guarded below
    const size_t abase = (size_t)arow * DD + lk * 8;

    f32x4 acc[8];
    #pragma unroll
    for (int t = 0; t < 8; ++t) acc[t] = (f32x4){0.f, 0.f, 0.f, 0.f};

    const bf16x8* wp = (const bf16x8*)Wp + l;

    #pragma unroll
    for (int kk = 0; kk < 8; ++kk) {
        bf16x8 afrag = (kk < 4)
            ? *(const bf16x8*)(Sb + abase + kk * 32)
            : *(const bf16x8*)(Xb + abase + (kk - 4) * 32);
        #pragma unroll
        for (int t = 0; t < 8; ++t) {
            bf16x8 bfrag = wp[(kk * 8 + t) * 64];
            acc[t] = __builtin_amdgcn_mfma_f32_16x16x32_bf16(afrag, bfrag, acc[t], 0, 0, 0);
        }
    }

    // bias per lane-column
    float bv[8];
    #pragma unroll
    for (int t = 0; t < 8; ++t) bv[t] = bl[t * 16 + lr];

    // C/D layout: col = t*16 + (l&15), row = (l>>4)*4 + j
    #pragma unroll
    for (int j = 0; j < 4; ++j) {
        float ss = 0.f;
        #pragma unroll
        for (int t = 0; t < 8; ++t) {
            acc[t][j] += bv[t];
            ss += acc[t][j] * acc[t][j];
        }
        ss += __shfl_xor(ss, 1);
        ss += __shfl_xor(ss, 2);
        ss += __shfl_xor(ss, 4);
        ss += __shfl_xor(ss, 8);
        float sc = 1.0f / fmaxf(sqrtf(ss), 1e-12f);

        int g = row0 + lk * 4 + j;
        if (g < n) {
            #pragma unroll
            for (int t = 0; t < 8; ++t) {
                float o = fmaxf(acc[t][j] * sc, 0.f);
                Y[(size_t)g * DD + t * 16 + lr] = o;
                if (writeH) Hb[(size_t)g * DD + t * 16 + lr] = f2b(o);
            }
        }
    }
}

// ===========================================================================
extern "C" void kernel_launch(void* const* d_in, const int* in_sizes, int n_in,
                              void* d_out, int out_size, void* d_ws, size_t ws_size,
                              hipStream_t stream)
{
    const float* x   = (const float*)d_in[0];
    const int*   ei  = (const int*)d_in[1];
    const float* Wl1 = (const float*)d_in[2];
    const float* bl1 = (const float*)d_in[3];
    const float* Wr1 = (const float*)d_in[4];
    const float* Wl2 = (const float*)d_in[5];
    const float* bl2 = (const float*)d_in[6];
    const float* Wr2 = (const float*)d_in[7];
    float* out = (float*)d_out;

    const int N = in_sizes[0] / DD;
    const int E = in_sizes[1] / 2;
    const int* src = ei;
    const int* dst = ei + E;

    // ---- workspace layout (~47 MB; round-2 proved >= 59.7 MB exists) ------
    char* w = (char*)d_ws;
    size_t off = 0;
    auto alloc = [&](size_t bytes) {
        void* p = w + off;
        off += (bytes + 255) & ~(size_t)255;
        return p;
    };
    unsigned short* xb   = (unsigned short*)alloc((size_t)N * DD * 2);  // also Hb
    unsigned short* Sb   = (unsigned short*)alloc((size_t)N * DD * 2);
    int*   csr    = (int*)  alloc((size_t)E * sizeof(int));
    int*   deg    = (int*)  alloc((size_t)N * sizeof(int));
    int*   inc    = (int*)  alloc((size_t)N * sizeof(int));
    int*   rowptr = (int*)  alloc((size_t)(N + 1) * sizeof(int));
    int*   cursor = (int*)  alloc((size_t)N * sizeof(int));
    float* invd   = (float*)alloc((size_t)N * sizeof(float));
    int*   bsum   = (int*)  alloc(512 * sizeof(int));
    unsigned short* Wp1 = (unsigned short*)alloc(4096 * 8 * 2);
    unsigned short* Wp2 = (unsigned short*)alloc(4096 * 8 * 2);
    (void)ws_size;

    const int nb = (N + 255) / 256;

    // ---- bf16 convert + CSR build (graph shared by both layers) -----------
    cvt_kernel  <<<(N * DD / 8 + 255) / 256, 256, 0, stream>>>(x, xb, N * DD / 8);
    hipMemsetAsync(deg, 0, (size_t)N * sizeof(int), stream);
    deg_kernel  <<<(E + 255) / 256, 256, 0, stream>>>(dst, deg, E);
    scan1_kernel<<<nb, 256, 0, stream>>>(deg, inc, bsum, N);
    scan2_kernel<<<1, 512, 0, stream>>>(bsum, nb);
    scan3_kernel<<<(N + 256) / 256, 256, 0, stream>>>(inc, bsum, deg,
                                                      rowptr, cursor, invd, N);
    fill_kernel <<<(E + 255) / 256, 256, 0, stream>>>(src, dst, cursor, csr, E);
    wprep_kernel<<<16, 256, 0, stream>>>(Wl1, Wr1, Wp1);
    wprep_kernel<<<16, 256, 0, stream>>>(Wl2, Wr2, Wp2);

    const int aggGrid = (N * 16 + 255) / 256;
    const int mmGrid  = (N + 63) / 64;

    // ---- layer 1: out = norm_relu([agg(xb)|xb] @ Wp1 + bl1); hb -> xb -----
    aggb_kernel<<<aggGrid, 256, 0, stream>>>(xb, csr, rowptr, invd, Sb, N);
    mmf_kernel <<<mmGrid, 256, 0, stream>>>(Sb, xb, Wp1, bl1, out, xb, N, 1);

    // ---- layer 2: out = norm_relu([agg(hb)|hb] @ Wp2 + bl2) ---------------
    aggb_kernel<<<aggGrid, 256, 0, stream>>>(xb, csr, rowptr, invd, Sb, N);
    mmf_kernel <<<mmGrid, 256, 0, stream>>>(Sb, xb, Wp2, bl2, out, xb, N, 0);
}

// Round 4
// 302.464 us; speedup vs baseline: 19.1800x; 1.3821x over previous
//
#include <hip/hip_runtime.h>

#define DD 128
#define NBMAX 2048          // max coarse buckets (supports N <= 131072)
#define EPB 16384           // edges per coarse block

typedef short bf16x8 __attribute__((ext_vector_type(8)));
typedef float f32x4  __attribute__((ext_vector_type(4)));

// ---- bf16 helpers (RNE) ----------------------------------------------------
static __device__ __forceinline__ unsigned short f2b(float f) {
    union { float f; unsigned u; } v; v.f = f;
    unsigned u = v.u;
    return (unsigned short)((u + 0x7FFFu + ((u >> 16) & 1u)) >> 16);
}
static __device__ __forceinline__ float blo(unsigned p) {
    union { unsigned u; float f; } v; v.u = p << 16; return v.f;
}
static __device__ __forceinline__ float bhi(unsigned p) {
    union { unsigned u; float f; } v; v.u = p & 0xFFFF0000u; return v.f;
}

// ===========================================================================
// x (fp32) -> xb (bf16), 8 elems/thread
// ===========================================================================
__global__ __launch_bounds__(256) void cvt_kernel(
    const float* __restrict__ X, unsigned short* __restrict__ Xb, int n8)
{
    int i = blockIdx.x * 256 + threadIdx.x;
    if (i >= n8) return;
    const float4* p = (const float4*)(X + (size_t)i * 8);
    float4 a = p[0], b = p[1];
    uint4 o;
    o.x = f2b(a.x) | ((unsigned)f2b(a.y) << 16);
    o.y = f2b(a.z) | ((unsigned)f2b(a.w) << 16);
    o.z = f2b(b.x) | ((unsigned)f2b(b.y) << 16);
    o.w = f2b(b.z) | ((unsigned)f2b(b.w) << 16);
    *(uint4*)(Xb + (size_t)i * 8) = o;
}

// ===========================================================================
// degree histogram + scan -> rowptr
// ===========================================================================
__global__ __launch_bounds__(256) void deg_kernel(
    const int* __restrict__ dst, int* __restrict__ deg, int nE)
{
    int e = blockIdx.x * 256 + threadIdx.x;
    if (e < nE) atomicAdd(&deg[dst[e]], 1);
}

__global__ __launch_bounds__(256) void scan1_kernel(
    const int* __restrict__ deg, int* __restrict__ inc,
    int* __restrict__ bsum, int n)
{
    __shared__ int tmp[256];
    int i = blockIdx.x * 256 + threadIdx.x;
    int t = threadIdx.x;
    tmp[t] = (i < n) ? deg[i] : 0;
    __syncthreads();
    for (int off = 1; off < 256; off <<= 1) {
        int v = (t >= off) ? tmp[t - off] : 0;
        __syncthreads();
        tmp[t] += v;
        __syncthreads();
    }
    if (i < n) inc[i] = tmp[t];
    if (t == 255) bsum[blockIdx.x] = tmp[255];
}

__global__ __launch_bounds__(512) void scan2_kernel(int* __restrict__ bsum, int nb)
{
    __shared__ int tmp[512];
    int t = threadIdx.x;
    tmp[t] = (t < nb) ? bsum[t] : 0;
    __syncthreads();
    for (int off = 1; off < 512; off <<= 1) {
        int v = (t >= off) ? tmp[t - off] : 0;
        __syncthreads();
        tmp[t] += v;
        __syncthreads();
    }
    if (t < nb) bsum[t] = (t == 0) ? 0 : tmp[t - 1];
}

__global__ __launch_bounds__(256) void scan3_kernel(
    const int* __restrict__ inc, const int* __restrict__ bsum,
    const int* __restrict__ deg, int* __restrict__ rowptr,
    int* __restrict__ cursor, float* __restrict__ invd, int n)
{
    int i = blockIdx.x * 256 + threadIdx.x;
    if (i > n) return;
    int rp = (i == 0) ? 0 : (inc[i - 1] + bsum[(i - 1) >> 8]);
    rowptr[i] = rp;
    if (i < n) {
        cursor[i] = rp;
        invd[i]   = 1.0f / fmaxf((float)deg[i], 1.0f);
    }
}

// gcur[b] = rowptr[64*b]  (coarse bucket base offsets)
__global__ __launch_bounds__(256) void binit_kernel(
    const int* __restrict__ rowptr, int* __restrict__ gcur, int nbuck)
{
    int b = blockIdx.x * 256 + threadIdx.x;
    if (b < nbuck) gcur[b] = rowptr[b * 64];
}

// ===========================================================================
// coarse bucket scatter with per-(block,bucket) chunk reservation.
// pairs[p] = src | ((dst&63) << 17), grouped by bucket (= dst>>6).
// Chunk writes are block-private -> temporally clustered, single-XCD.
// ===========================================================================
__global__ __launch_bounds__(1024) void coarse_kernel(
    const int* __restrict__ src, const int* __restrict__ dst,
    int* __restrict__ gcur, int* __restrict__ pairs, int nE, int nbuck)
{
    __shared__ int hist[NBMAX];
    const int tid = threadIdx.x;
    const int e0 = blockIdx.x * EPB;
    const int e1 = min(e0 + EPB, nE);

    for (int b = tid; b < nbuck; b += 1024) hist[b] = 0;
    __syncthreads();

    for (int e = e0 + tid; e < e1; e += 1024)
        atomicAdd(&hist[dst[e] >> 6], 1);
    __syncthreads();

    for (int b = tid; b < nbuck; b += 1024) {
        int c = hist[b];
        hist[b] = c ? atomicAdd(&gcur[b], c) : 0;
    }
    __syncthreads();

    for (int e = e0 + tid; e < e1; e += 1024) {
        int d = dst[e];
        int p = atomicAdd(&hist[d >> 6], 1);
        pairs[p] = src[e] | ((d & 63) << 17);
    }
}

// ===========================================================================
// fine pass: one block per bucket; scatter src into csr within the bucket's
// contiguous (L2-hot, block-private) window, grouped exactly by dst node.
// ===========================================================================
__global__ __launch_bounds__(256) void fine_kernel(
    const int* __restrict__ pairs, const int* __restrict__ rowptr,
    int* __restrict__ csr, int n)
{
    __shared__ int cur[64];
    const int tid   = threadIdx.x;
    const int node0 = blockIdx.x * 64;
    const int nn    = min(64, n - node0);
    if (tid < nn) cur[tid] = rowptr[node0 + tid];
    __syncthreads();
    const int rs = rowptr[node0];
    const int re = rowptr[node0 + nn];
    for (int j = rs + tid; j < re; j += 256) {
        int e = pairs[j];
        int p = atomicAdd(&cur[e >> 17], 1);
        csr[p] = e & 131071;
    }
}

// fallback fill (N > 131072): original global-cursor scatter
__global__ __launch_bounds__(256) void fill_kernel(
    const int* __restrict__ src, const int* __restrict__ dst,
    int* __restrict__ cursor, int* __restrict__ csr, int nE)
{
    int e = blockIdx.x * 256 + threadIdx.x;
    if (e < nE) {
        int pos = atomicAdd(&cursor[dst[e]], 1);
        csr[pos] = src[e];
    }
}

// ===========================================================================
// W permute: Wp[kk(8)][nt(8)][lane(64)][j(8)] = bf16(Wcat[k][c])
// ===========================================================================
__global__ __launch_bounds__(256) void wprep_kernel(
    const float* __restrict__ Wl, const float* __restrict__ Wr,
    unsigned short* __restrict__ Wp)
{
    int t = blockIdx.x * 256 + threadIdx.x;
    if (t >= 4096) return;
    int l  = t & 63;
    int nt = (t >> 6) & 7;
    int kk = t >> 9;
    int c  = nt * 16 + (l & 15);
    int k0 = kk * 32 + (l >> 4) * 8;
    unsigned short o[8];
    #pragma unroll
    for (int j = 0; j < 8; ++j) {
        int k = k0 + j;
        float v = (k < 128) ? Wl[k * 128 + c] : Wr[(k - 128) * 128 + c];
        o[j] = f2b(v);
    }
    uint4 pk;
    pk.x = o[0] | ((unsigned)o[1] << 16);
    pk.y = o[2] | ((unsigned)o[3] << 16);
    pk.z = o[4] | ((unsigned)o[5] << 16);
    pk.w = o[6] | ((unsigned)o[7] << 16);
    *(uint4*)(Wp + (size_t)t * 8) = pk;
}

// ===========================================================================
// gather-aggregate (bf16), 16 lanes/node, edge loop unrolled x4 (4 outstanding
// 256B row gathers per group), two independent accumulator sets.
// ===========================================================================
static __device__ __forceinline__ void acc8(float* a, uint4 v) {
    a[0] += blo(v.x); a[1] += bhi(v.x);
    a[2] += blo(v.y); a[3] += bhi(v.y);
    a[4] += blo(v.z); a[5] += bhi(v.z);
    a[6] += blo(v.w); a[7] += bhi(v.w);
}

__global__ __launch_bounds__(256) void aggb_kernel(
    const unsigned short* __restrict__ Xb, const int* __restrict__ csr,
    const int* __restrict__ rowptr, const float* __restrict__ invd,
    unsigned short* __restrict__ Sb, int n)
{
    int node = (blockIdx.x * 256 + threadIdx.x) >> 4;
    int l    = threadIdx.x & 15;
    if (node >= n) return;
    int beg = rowptr[node], end = rowptr[node + 1];

    float a[8], b[8];
    #pragma unroll
    for (int i = 0; i < 8; ++i) { a[i] = 0.f; b[i] = 0.f; }

    int j = beg;
    for (; j + 4 <= end; j += 4) {
        int s0 = csr[j + 0], s1 = csr[j + 1];
        int s2 = csr[j + 2], s3 = csr[j + 3];
        uint4 v0 = *(const uint4*)(Xb + (size_t)s0 * DD + l * 8);
        uint4 v1 = *(const uint4*)(Xb + (size_t)s1 * DD + l * 8);
        uint4 v2 = *(const uint4*)(Xb + (size_t)s2 * DD + l * 8);
        uint4 v3 = *(const uint4*)(Xb + (size_t)s3 * DD + l * 8);
        acc8(a, v0); acc8(b, v1); acc8(a, v2); acc8(b, v3);
    }
    for (; j < end; ++j) {
        uint4 v = *(const uint4*)(Xb + (size_t)csr[j] * DD + l * 8);
        acc8(a, v);
    }

    float iv = invd[node];
    float r[8];
    #pragma unroll
    for (int i = 0; i < 8; ++i) r[i] = (a[i] + b[i]) * iv;
    uint4 o;
    o.x = f2b(r[0]) | ((unsigned)f2b(r[1]) << 16);
    o.y = f2b(r[2]) | ((unsigned)f2b(r[3]) << 16);
    o.z = f2b(r[4]) | ((unsigned)f2b(r[5]) << 16);
    o.w = f2b(r[6]) | ((unsigned)f2b(r[7]) << 16);
    *(uint4*)(Sb + (size_t)node * DD + l * 8) = o;
}

// ===========================================================================
// MFMA GEMM + fused bias / L2-normalize / ReLU.
//   Y[i] = norm_relu( Sb[i] @ Wl + bl + Xb[i] @ Wr )   via [Sb|Xb] @ Wp
// ===========================================================================
__global__ __launch_bounds__(256) void mmf_kernel(
    const unsigned short* __restrict__ Sb,
    const unsigned short* Xb,            // may alias Hb
    const unsigned short* __restrict__ Wp,
    const float* __restrict__ bl,
    float* __restrict__ Y,
    unsigned short* Hb,
    int n, int writeH)
{
    const int wid  = threadIdx.x >> 6;
    const int l    = threadIdx.x & 63;
    const int row0 = blockIdx.x * 64 + wid * 16;
    const int lr   = l & 15;
    const int lk   = l >> 4;

    int arow = row0 + lr;
    if (arow >= n) arow = n - 1;
    const size_t abase = (size_t)arow * DD + lk * 8;

    f32x4 acc[8];
    #pragma unroll
    for (int t = 0; t < 8; ++t) acc[t] = (f32x4){0.f, 0.f, 0.f, 0.f};

    const bf16x8* wp = (const bf16x8*)Wp + l;

    #pragma unroll
    for (int kk = 0; kk < 8; ++kk) {
        bf16x8 afrag = (kk < 4)
            ? *(const bf16x8*)(Sb + abase + kk * 32)
            : *(const bf16x8*)(Xb + abase + (kk - 4) * 32);
        #pragma unroll
        for (int t = 0; t < 8; ++t) {
            bf16x8 bfrag = wp[(kk * 8 + t) * 64];
            acc[t] = __builtin_amdgcn_mfma_f32_16x16x32_bf16(afrag, bfrag, acc[t], 0, 0, 0);
        }
    }

    float bv[8];
    #pragma unroll
    for (int t = 0; t < 8; ++t) bv[t] = bl[t * 16 + lr];

    #pragma unroll
    for (int j = 0; j < 4; ++j) {
        float ss = 0.f;
        #pragma unroll
        for (int t = 0; t < 8; ++t) {
            acc[t][j] += bv[t];
            ss += acc[t][j] * acc[t][j];
        }
        ss += __shfl_xor(ss, 1);
        ss += __shfl_xor(ss, 2);
        ss += __shfl_xor(ss, 4);
        ss += __shfl_xor(ss, 8);
        float sc = 1.0f / fmaxf(sqrtf(ss), 1e-12f);

        int g = row0 + lk * 4 + j;
        if (g < n) {
            #pragma unroll
            for (int t = 0; t < 8; ++t) {
                float o = fmaxf(acc[t][j] * sc, 0.f);
                Y[(size_t)g * DD + t * 16 + lr] = o;
                if (writeH) Hb[(size_t)g * DD + t * 16 + lr] = f2b(o);
            }
        }
    }
}

// ===========================================================================
extern "C" void kernel_launch(void* const* d_in, const int* in_sizes, int n_in,
                              void* d_out, int out_size, void* d_ws, size_t ws_size,
                              hipStream_t stream)
{
    const float* x   = (const float*)d_in[0];
    const int*   ei  = (const int*)d_in[1];
    const float* Wl1 = (const float*)d_in[2];
    const float* bl1 = (const float*)d_in[3];
    const float* Wr1 = (const float*)d_in[4];
    const float* Wl2 = (const float*)d_in[5];
    const float* bl2 = (const float*)d_in[6];
    const float* Wr2 = (const float*)d_in[7];
    float* out = (float*)d_out;

    const int N = in_sizes[0] / DD;
    const int E = in_sizes[1] / 2;
    const int* src = ei;
    const int* dst = ei + E;

    // ---- workspace layout (~59.4 MB, same as round 3) ----------------------
    char* w = (char*)d_ws;
    size_t off = 0;
    auto alloc = [&](size_t bytes) {
        void* p = w + off;
        off += (bytes + 255) & ~(size_t)255;
        return p;
    };
    unsigned short* xb   = (unsigned short*)alloc((size_t)N * DD * 2);  // also Hb
    unsigned short* Sb   = (unsigned short*)alloc((size_t)N * DD * 2);
    int*   csr    = (int*)  alloc((size_t)E * sizeof(int));
    int*   deg    = (int*)  alloc((size_t)N * sizeof(int));
    int*   inc    = (int*)  alloc((size_t)N * sizeof(int));
    int*   rowptr = (int*)  alloc((size_t)(N + 1) * sizeof(int));
    int*   cursor = (int*)  alloc((size_t)N * sizeof(int));
    float* invd   = (float*)alloc((size_t)N * sizeof(float));
    int*   bsum   = (int*)  alloc(512 * sizeof(int));
    unsigned short* Wp1 = (unsigned short*)alloc(4096 * 8 * 2);
    unsigned short* Wp2 = (unsigned short*)alloc(4096 * 8 * 2);
    int*   gcur   = (int*)  alloc(NBMAX * sizeof(int));
    int*   pairs  = (int*)Sb;            // alias: Sb not live during CSR build
    (void)ws_size;

    const int nb    = (N + 255) / 256;       // scan blocks
    const int nbuck = (N + 63) / 64;         // coarse buckets

    // ---- bf16 convert + CSR build ------------------------------------------
    cvt_kernel  <<<(N * DD / 8 + 255) / 256, 256, 0, stream>>>(x, xb, N * DD / 8);
    hipMemsetAsync(deg, 0, (size_t)N * sizeof(int), stream);
    deg_kernel  <<<(E + 255) / 256, 256, 0, stream>>>(dst, deg, E);
    scan1_kernel<<<nb, 256, 0, stream>>>(deg, inc, bsum, N);
    scan2_kernel<<<1, 512, 0, stream>>>(bsum, nb);
    scan3_kernel<<<(N + 256) / 256, 256, 0, stream>>>(inc, bsum, deg,
                                                      rowptr, cursor, invd, N);
    if (N <= 131072 && nbuck <= NBMAX) {
        binit_kernel <<<(nbuck + 255) / 256, 256, 0, stream>>>(rowptr, gcur, nbuck);
        coarse_kernel<<<(E + EPB - 1) / EPB, 1024, 0, stream>>>(src, dst, gcur,
                                                                pairs, E, nbuck);
        fine_kernel  <<<nbuck, 256, 0, stream>>>(pairs, rowptr, csr, N);
    } else {
        fill_kernel  <<<(E + 255) / 256, 256, 0, stream>>>(src, dst, cursor, csr, E);
    }
    wprep_kernel<<<16, 256, 0, stream>>>(Wl1, Wr1, Wp1);
    wprep_kernel<<<16, 256, 0, stream>>>(Wl2, Wr2, Wp2);

    const int aggGrid = (N * 16 + 255) / 256;
    const int mmGrid  = (N + 63) / 64;

    // ---- layer 1: out = norm_relu([agg(xb)|xb] @ Wp1 + bl1); hb -> xb ------
    aggb_kernel<<<aggGrid, 256, 0, stream>>>(xb, csr, rowptr, invd, Sb, N);
    mmf_kernel <<<mmGrid, 256, 0, stream>>>(Sb, xb, Wp1, bl1, out, xb, N, 1);

    // ---- layer 2: out = norm_relu([agg(hb)|hb] @ Wp2 + bl2) ----------------
    aggb_kernel<<<aggGrid, 256, 0, stream>>>(xb, csr, rowptr, invd, Sb, N);
    mmf_kernel <<<mmGrid, 256, 0, stream>>>(Sb, xb, Wp2, bl2, out, xb, N, 0);
}

// Round 5
// 241.055 us; speedup vs baseline: 24.0662x; 1.2548x over previous
//
#include <hip/hip_runtime.h>

#define DD 128
#define NBMAX 2048          // max coarse buckets (supports N <= 131072)
#define EPB 16384           // edges per coarse block

typedef short bf16x8 __attribute__((ext_vector_type(8)));
typedef float f32x4  __attribute__((ext_vector_type(4)));

// ---- bf16 helpers (RNE) ----------------------------------------------------
static __device__ __forceinline__ unsigned short f2b(float f) {
    union { float f; unsigned u; } v; v.f = f;
    unsigned u = v.u;
    return (unsigned short)((u + 0x7FFFu + ((u >> 16) & 1u)) >> 16);
}
static __device__ __forceinline__ float blo(unsigned p) {
    union { unsigned u; float f; } v; v.u = p << 16; return v.f;
}
static __device__ __forceinline__ float bhi(unsigned p) {
    union { unsigned u; float f; } v; v.u = p & 0xFFFF0000u; return v.f;
}

// ===========================================================================
// x (fp32) -> xb (bf16), 8 elems/thread
// ===========================================================================
__global__ __launch_bounds__(256) void cvt_kernel(
    const float* __restrict__ X, unsigned short* __restrict__ Xb, int n8)
{
    int i = blockIdx.x * 256 + threadIdx.x;
    if (i >= n8) return;
    const float4* p = (const float4*)(X + (size_t)i * 8);
    float4 a = p[0], b = p[1];
    uint4 o;
    o.x = f2b(a.x) | ((unsigned)f2b(a.y) << 16);
    o.y = f2b(a.z) | ((unsigned)f2b(a.w) << 16);
    o.z = f2b(b.x) | ((unsigned)f2b(b.y) << 16);
    o.w = f2b(b.z) | ((unsigned)f2b(b.w) << 16);
    *(uint4*)(Xb + (size_t)i * 8) = o;
}

// ===========================================================================
// bucket histogram: LDS-privatized counts of dst>>6, one global atomic per
// (block,bucket). Replaces the 1.6M-atomic per-node degree histogram.
// ===========================================================================
__global__ __launch_bounds__(1024) void bhist_kernel(
    const int* __restrict__ dst, int* __restrict__ bcnt, int nE, int nbuck)
{
    __shared__ int hist[NBMAX];
    const int tid = threadIdx.x;
    const int e0 = blockIdx.x * EPB;
    const int e1 = min(e0 + EPB, nE);

    for (int b = tid; b < nbuck; b += 1024) hist[b] = 0;
    __syncthreads();
    for (int e = e0 + tid; e < e1; e += 1024)
        atomicAdd(&hist[dst[e] >> 6], 1);
    __syncthreads();
    for (int b = tid; b < nbuck; b += 1024) {
        int c = hist[b];
        if (c) atomicAdd(&bcnt[b], c);
    }
}

// single-block exclusive scan of bucket counts -> bbase[nbuck+1], gcur copy;
// also writes rowptr[n] = E.
__global__ __launch_bounds__(1024) void bscan_kernel(
    const int* __restrict__ bcnt, int* __restrict__ bbase,
    int* __restrict__ gcur, int* __restrict__ rowptr, int nbuck, int n, int nE)
{
    __shared__ int tmp[1024];
    __shared__ int carry;
    int t = threadIdx.x;
    if (t == 0) carry = 0;
    __syncthreads();
    for (int c0 = 0; c0 < nbuck; c0 += 1024) {
        int v = (c0 + t < nbuck) ? bcnt[c0 + t] : 0;
        tmp[t] = v;
        __syncthreads();
        for (int off = 1; off < 1024; off <<= 1) {
            int u = (t >= off) ? tmp[t - off] : 0;
            __syncthreads();
            tmp[t] += u;
            __syncthreads();
        }
        int excl = carry + tmp[t] - v;
        if (c0 + t < nbuck) { bbase[c0 + t] = excl; gcur[c0 + t] = excl; }
        __syncthreads();
        if (t == 1023) carry += tmp[1023];
        __syncthreads();
    }
    if (t == 0) { bbase[nbuck] = nE; rowptr[n] = nE; }
}

// ===========================================================================
// coarse bucket scatter with per-(block,bucket) chunk reservation.
// pairs[p] = src | ((dst&63) << 17), grouped by bucket (= dst>>6).
// ===========================================================================
__global__ __launch_bounds__(1024) void coarse_kernel(
    const int* __restrict__ src, const int* __restrict__ dst,
    int* __restrict__ gcur, int* __restrict__ pairs, int nE, int nbuck)
{
    __shared__ int hist[NBMAX];
    const int tid = threadIdx.x;
    const int e0 = blockIdx.x * EPB;
    const int e1 = min(e0 + EPB, nE);

    for (int b = tid; b < nbuck; b += 1024) hist[b] = 0;
    __syncthreads();
    for (int e = e0 + tid; e < e1; e += 1024)
        atomicAdd(&hist[dst[e] >> 6], 1);
    __syncthreads();
    for (int b = tid; b < nbuck; b += 1024) {
        int c = hist[b];
        hist[b] = c ? atomicAdd(&gcur[b], c) : 0;
    }
    __syncthreads();
    for (int e = e0 + tid; e < e1; e += 1024) {
        int d = dst[e];
        int p = atomicAdd(&hist[d >> 6], 1);
        pairs[p] = src[e] | ((d & 63) << 17);
    }
}

// ===========================================================================
// fine pass: one block per bucket. Derives per-node degree / rowptr / invd
// from its private pairs window (no global atomics), then scatters csr.
// ===========================================================================
__global__ __launch_bounds__(256) void fine_kernel(
    const int* __restrict__ pairs, const int* __restrict__ bbase,
    int* __restrict__ rowptr, float* __restrict__ invd,
    int* __restrict__ csr, int n)
{
    __shared__ int cnt[64];
    __shared__ int excl[64];
    __shared__ int cur[64];
    const int tid   = threadIdx.x;
    const int node0 = blockIdx.x * 64;
    const int nn    = min(64, n - node0);
    const int base  = bbase[blockIdx.x];
    const int wend  = bbase[blockIdx.x + 1];

    if (tid < 64) cnt[tid] = 0;
    __syncthreads();
    for (int j = base + tid; j < wend; j += 256)
        atomicAdd(&cnt[pairs[j] >> 17], 1);
    __syncthreads();
    if (tid == 0) {
        int run = 0;
        #pragma unroll
        for (int i = 0; i < 64; ++i) { excl[i] = run; run += cnt[i]; }
    }
    __syncthreads();
    if (tid < nn) {
        int rp = base + excl[tid];
        rowptr[node0 + tid] = rp;
        cur[tid] = rp;
        invd[node0 + tid] = 1.0f / fmaxf((float)cnt[tid], 1.0f);
    }
    __syncthreads();
    for (int j = base + tid; j < wend; j += 256) {
        int e = pairs[j];
        int p = atomicAdd(&cur[e >> 17], 1);
        csr[p] = e & 131071;
    }
}

// ===========================================================================
// fallback path kernels (N > 131072): per-node atomic histogram + scans + fill
// ===========================================================================
__global__ __launch_bounds__(256) void deg_kernel(
    const int* __restrict__ dst, int* __restrict__ deg, int nE)
{
    int e = blockIdx.x * 256 + threadIdx.x;
    if (e < nE) atomicAdd(&deg[dst[e]], 1);
}

__global__ __launch_bounds__(256) void scan1_kernel(
    const int* __restrict__ deg, int* __restrict__ inc,
    int* __restrict__ bsum, int n)
{
    __shared__ int tmp[256];
    int i = blockIdx.x * 256 + threadIdx.x;
    int t = threadIdx.x;
    tmp[t] = (i < n) ? deg[i] : 0;
    __syncthreads();
    for (int off = 1; off < 256; off <<= 1) {
        int v = (t >= off) ? tmp[t - off] : 0;
        __syncthreads();
        tmp[t] += v;
        __syncthreads();
    }
    if (i < n) inc[i] = tmp[t];
    if (t == 255) bsum[blockIdx.x] = tmp[255];
}

__global__ __launch_bounds__(512) void scan2_kernel(int* __restrict__ bsum, int nb)
{
    __shared__ int tmp[512];
    int t = threadIdx.x;
    tmp[t] = (t < nb) ? bsum[t] : 0;
    __syncthreads();
    for (int off = 1; off < 512; off <<= 1) {
        int v = (t >= off) ? tmp[t - off] : 0;
        __syncthreads();
        tmp[t] += v;
        __syncthreads();
    }
    if (t < nb) bsum[t] = (t == 0) ? 0 : tmp[t - 1];
}

__global__ __launch_bounds__(256) void scan3_kernel(
    const int* __restrict__ inc, const int* __restrict__ bsum,
    const int* __restrict__ deg, int* __restrict__ rowptr,
    int* __restrict__ cursor, float* __restrict__ invd, int n)
{
    int i = blockIdx.x * 256 + threadIdx.x;
    if (i > n) return;
    int rp = (i == 0) ? 0 : (inc[i - 1] + bsum[(i - 1) >> 8]);
    rowptr[i] = rp;
    if (i < n) {
        cursor[i] = rp;
        invd[i]   = 1.0f / fmaxf((float)deg[i], 1.0f);
    }
}

__global__ __launch_bounds__(256) void fill_kernel(
    const int* __restrict__ src, const int* __restrict__ dst,
    int* __restrict__ cursor, int* __restrict__ csr, int nE)
{
    int e = blockIdx.x * 256 + threadIdx.x;
    if (e < nE) {
        int pos = atomicAdd(&cursor[dst[e]], 1);
        csr[pos] = src[e];
    }
}

// ===========================================================================
// W permute: Wp[kk(8)][nt(8)][lane(64)][j(8)] = bf16(Wcat[k][c])
// ===========================================================================
__global__ __launch_bounds__(256) void wprep_kernel(
    const float* __restrict__ Wl, const float* __restrict__ Wr,
    unsigned short* __restrict__ Wp)
{
    int t = blockIdx.x * 256 + threadIdx.x;
    if (t >= 4096) return;
    int l  = t & 63;
    int nt = (t >> 6) & 7;
    int kk = t >> 9;
    int c  = nt * 16 + (l & 15);
    int k0 = kk * 32 + (l >> 4) * 8;
    unsigned short o[8];
    #pragma unroll
    for (int j = 0; j < 8; ++j) {
        int k = k0 + j;
        float v = (k < 128) ? Wl[k * 128 + c] : Wr[(k - 128) * 128 + c];
        o[j] = f2b(v);
    }
    uint4 pk;
    pk.x = o[0] | ((unsigned)o[1] << 16);
    pk.y = o[2] | ((unsigned)o[3] << 16);
    pk.z = o[4] | ((unsigned)o[5] << 16);
    pk.w = o[6] | ((unsigned)o[7] << 16);
    *(uint4*)(Wp + (size_t)t * 8) = pk;
}

// ===========================================================================
// gather-aggregate (bf16), 16 lanes/node, unrolled x8 (8 outstanding 256B
// row gathers per group), two accumulator sets.
// ===========================================================================
static __device__ __forceinline__ void acc8(float* a, uint4 v) {
    a[0] += blo(v.x); a[1] += bhi(v.x);
    a[2] += blo(v.y); a[3] += bhi(v.y);
    a[4] += blo(v.z); a[5] += bhi(v.z);
    a[6] += blo(v.w); a[7] += bhi(v.w);
}

__global__ __launch_bounds__(256) void aggb_kernel(
    const unsigned short* __restrict__ Xb, const int* __restrict__ csr,
    const int* __restrict__ rowptr, const float* __restrict__ invd,
    unsigned short* __restrict__ Sb, int n)
{
    int node = (blockIdx.x * 256 + threadIdx.x) >> 4;
    int l    = threadIdx.x & 15;
    if (node >= n) return;
    int beg = rowptr[node], end = rowptr[node + 1];

    float a[8], b[8];
    #pragma unroll
    for (int i = 0; i < 8; ++i) { a[i] = 0.f; b[i] = 0.f; }

    int j = beg;
    for (; j + 8 <= end; j += 8) {
        int s[8];
        #pragma unroll
        for (int q = 0; q < 8; ++q) s[q] = csr[j + q];
        uint4 v[8];
        #pragma unroll
        for (int q = 0; q < 8; ++q)
            v[q] = *(const uint4*)(Xb + (size_t)s[q] * DD + l * 8);
        #pragma unroll
        for (int q = 0; q < 8; ++q) acc8((q & 1) ? b : a, v[q]);
    }
    for (; j + 2 <= end; j += 2) {
        int s0 = csr[j], s1 = csr[j + 1];
        uint4 v0 = *(const uint4*)(Xb + (size_t)s0 * DD + l * 8);
        uint4 v1 = *(const uint4*)(Xb + (size_t)s1 * DD + l * 8);
        acc8(a, v0); acc8(b, v1);
    }
    if (j < end) {
        uint4 v = *(const uint4*)(Xb + (size_t)csr[j] * DD + l * 8);
        acc8(a, v);
    }

    float iv = invd[node];
    float r[8];
    #pragma unroll
    for (int i = 0; i < 8; ++i) r[i] = (a[i] + b[i]) * iv;
    uint4 o;
    o.x = f2b(r[0]) | ((unsigned)f2b(r[1]) << 16);
    o.y = f2b(r[2]) | ((unsigned)f2b(r[3]) << 16);
    o.z = f2b(r[4]) | ((unsigned)f2b(r[5]) << 16);
    o.w = f2b(r[6]) | ((unsigned)f2b(r[7]) << 16);
    *(uint4*)(Sb + (size_t)node * DD + l * 8) = o;
}

// ===========================================================================
// MFMA GEMM + fused bias / L2-normalize / ReLU.
//   norm_relu( Sb[i] @ Wl + bl + Xb[i] @ Wr )  -> Y (fp32) and/or Hb (bf16)
// ===========================================================================
__global__ __launch_bounds__(256) void mmf_kernel(
    const unsigned short* __restrict__ Sb,
    const unsigned short* Xb,            // may alias Hb
    const unsigned short* __restrict__ Wp,
    const float* __restrict__ bl,
    float* __restrict__ Y,
    unsigned short* Hb,
    int n, int writeY, int writeH)
{
    const int wid  = threadIdx.x >> 6;
    const int l    = threadIdx.x & 63;
    const int row0 = blockIdx.x * 64 + wid * 16;
    const int lr   = l & 15;
    const int lk   = l >> 4;

    int arow = row0 + lr;
    if (arow >= n) arow = n - 1;
    const size_t abase = (size_t)arow * DD + lk * 8;

    f32x4 acc[8];
    #pragma unroll
    for (int t = 0; t < 8; ++t) acc[t] = (f32x4){0.f, 0.f, 0.f, 0.f};

    const bf16x8* wp = (const bf16x8*)Wp + l;

    #pragma unroll
    for (int kk = 0; kk < 8; ++kk) {
        bf16x8 afrag = (kk < 4)
            ? *(const bf16x8*)(Sb + abase + kk * 32)
            : *(const bf16x8*)(Xb + abase + (kk - 4) * 32);
        #pragma unroll
        for (int t = 0; t < 8; ++t) {
            bf16x8 bfrag = wp[(kk * 8 + t) * 64];
            acc[t] = __builtin_amdgcn_mfma_f32_16x16x32_bf16(afrag, bfrag, acc[t], 0, 0, 0);
        }
    }

    float bv[8];
    #pragma unroll
    for (int t = 0; t < 8; ++t) bv[t] = bl[t * 16 + lr];

    #pragma unroll
    for (int j = 0; j < 4; ++j) {
        float ss = 0.f;
        #pragma unroll
        for (int t = 0; t < 8; ++t) {
            acc[t][j] += bv[t];
            ss += acc[t][j] * acc[t][j];
        }
        ss += __shfl_xor(ss, 1);
        ss += __shfl_xor(ss, 2);
        ss += __shfl_xor(ss, 4);
        ss += __shfl_xor(ss, 8);
        float sc = 1.0f / fmaxf(sqrtf(ss), 1e-12f);

        int g = row0 + lk * 4 + j;
        if (g < n) {
            #pragma unroll
            for (int t = 0; t < 8; ++t) {
                float o = fmaxf(acc[t][j] * sc, 0.f);
                if (writeY) Y[(size_t)g * DD + t * 16 + lr] = o;
                if (writeH) Hb[(size_t)g * DD + t * 16 + lr] = f2b(o);
            }
        }
    }
}

// ===========================================================================
extern "C" void kernel_launch(void* const* d_in, const int* in_sizes, int n_in,
                              void* d_out, int out_size, void* d_ws, size_t ws_size,
                              hipStream_t stream)
{
    const float* x   = (const float*)d_in[0];
    const int*   ei  = (const int*)d_in[1];
    const float* Wl1 = (const float*)d_in[2];
    const float* bl1 = (const float*)d_in[3];
    const float* Wr1 = (const float*)d_in[4];
    const float* Wl2 = (const float*)d_in[5];
    const float* bl2 = (const float*)d_in[6];
    const float* Wr2 = (const float*)d_in[7];
    float* out = (float*)d_out;

    const int N = in_sizes[0] / DD;
    const int E = in_sizes[1] / 2;
    const int* src = ei;
    const int* dst = ei + E;

    // ---- workspace layout --------------------------------------------------
    char* w = (char*)d_ws;
    size_t off = 0;
    auto alloc = [&](size_t bytes) {
        void* p = w + off;
        off += (bytes + 255) & ~(size_t)255;
        return p;
    };
    unsigned short* xb   = (unsigned short*)alloc((size_t)N * DD * 2);  // also Hb
    unsigned short* Sb   = (unsigned short*)alloc((size_t)N * DD * 2);
    int*   csr    = (int*)  alloc((size_t)E * sizeof(int));
    int*   deg    = (int*)  alloc((size_t)N * sizeof(int));
    int*   inc    = (int*)  alloc((size_t)N * sizeof(int));
    int*   rowptr = (int*)  alloc((size_t)(N + 1) * sizeof(int));
    int*   cursor = (int*)  alloc((size_t)N * sizeof(int));
    float* invd   = (float*)alloc((size_t)N * sizeof(float));
    int*   bsum   = (int*)  alloc(512 * sizeof(int));
    unsigned short* Wp1 = (unsigned short*)alloc(4096 * 8 * 2);
    unsigned short* Wp2 = (unsigned short*)alloc(4096 * 8 * 2);
    int*   gcur   = (int*)  alloc(NBMAX * sizeof(int));
    int*   bcnt   = (int*)  alloc(NBMAX * sizeof(int));
    int*   bbase  = (int*)  alloc((NBMAX + 1) * sizeof(int));
    int*   pairs  = (int*)Sb;            // alias: Sb not live during CSR build
    (void)ws_size;

    const int nbuck = (N + 63) / 64;
    const int nebl  = (E + EPB - 1) / EPB;

    cvt_kernel<<<(N * DD / 8 + 255) / 256, 256, 0, stream>>>(x, xb, N * DD / 8);

    if (N <= 131072 && nbuck <= NBMAX) {
        // ---- atomic-light CSR build ----------------------------------------
        hipMemsetAsync(bcnt, 0, (size_t)nbuck * sizeof(int), stream);
        bhist_kernel <<<nebl, 1024, 0, stream>>>(dst, bcnt, E, nbuck);
        bscan_kernel <<<1, 1024, 0, stream>>>(bcnt, bbase, gcur, rowptr, nbuck, N, E);
        coarse_kernel<<<nebl, 1024, 0, stream>>>(src, dst, gcur, pairs, E, nbuck);
        fine_kernel  <<<nbuck, 256, 0, stream>>>(pairs, bbase, rowptr, invd, csr, N);
    } else {
        // ---- fallback: per-node atomic histogram + scans + fill ------------
        const int nb = (N + 255) / 256;
        hipMemsetAsync(deg, 0, (size_t)N * sizeof(int), stream);
        deg_kernel  <<<(E + 255) / 256, 256, 0, stream>>>(dst, deg, E);
        scan1_kernel<<<nb, 256, 0, stream>>>(deg, inc, bsum, N);
        scan2_kernel<<<1, 512, 0, stream>>>(bsum, nb);
        scan3_kernel<<<(N + 256) / 256, 256, 0, stream>>>(inc, bsum, deg,
                                                          rowptr, cursor, invd, N);
        fill_kernel <<<(E + 255) / 256, 256, 0, stream>>>(src, dst, cursor, csr, E);
    }
    wprep_kernel<<<16, 256, 0, stream>>>(Wl1, Wr1, Wp1);
    wprep_kernel<<<16, 256, 0, stream>>>(Wl2, Wr2, Wp2);

    const int aggGrid = (N * 16 + 255) / 256;
    const int mmGrid  = (N + 63) / 64;

    // ---- layer 1: hb(xb) = bf16(norm_relu([agg(xb)|xb] @ Wp1 + bl1)) -------
    // fp32 Y store skipped: layer 2 overwrites it (dead store).
    aggb_kernel<<<aggGrid, 256, 0, stream>>>(xb, csr, rowptr, invd, Sb, N);
    mmf_kernel <<<mmGrid, 256, 0, stream>>>(Sb, xb, Wp1, bl1, out, xb, N, 0, 1);

    // ---- layer 2: out = norm_relu([agg(hb)|hb] @ Wp2 + bl2) ----------------
    aggb_kernel<<<aggGrid, 256, 0, stream>>>(xb, csr, rowptr, invd, Sb, N);
    mmf_kernel <<<mmGrid, 256, 0, stream>>>(Sb, xb, Wp2, bl2, out, xb, N, 1, 0);
}

// Round 6
// 236.156 us; speedup vs baseline: 24.5653x; 1.0207x over previous
//
#include <hip/hip_runtime.h>

#define DD 128
#define NBMAX 2048          // max coarse buckets (supports N <= 131072)
#define EPB 16384           // edges per coarse block

typedef short bf16x8 __attribute__((ext_vector_type(8)));
typedef float f32x4  __attribute__((ext_vector_type(4)));

// ---- bf16 helpers (RNE) ----------------------------------------------------
static __device__ __forceinline__ unsigned short f2b(float f) {
    union { float f; unsigned u; } v; v.f = f;
    unsigned u = v.u;
    return (unsigned short)((u + 0x7FFFu + ((u >> 16) & 1u)) >> 16);
}
static __device__ __forceinline__ float blo(unsigned p) {
    union { unsigned u; float f; } v; v.u = p << 16; return v.f;
}
static __device__ __forceinline__ float bhi(unsigned p) {
    union { unsigned u; float f; } v; v.u = p & 0xFFFF0000u; return v.f;
}

// ===========================================================================
// x (fp32) -> xb (bf16), 8 elems/thread
// ===========================================================================
__global__ __launch_bounds__(256) void cvt_kernel(
    const float* __restrict__ X, unsigned short* __restrict__ Xb, int n8)
{
    int i = blockIdx.x * 256 + threadIdx.x;
    if (i >= n8) return;
    const float4* p = (const float4*)(X + (size_t)i * 8);
    float4 a = p[0], b = p[1];
    uint4 o;
    o.x = f2b(a.x) | ((unsigned)f2b(a.y) << 16);
    o.y = f2b(a.z) | ((unsigned)f2b(a.w) << 16);
    o.z = f2b(b.x) | ((unsigned)f2b(b.y) << 16);
    o.w = f2b(b.z) | ((unsigned)f2b(b.w) << 16);
    *(uint4*)(Xb + (size_t)i * 8) = o;
}

// ===========================================================================
// bucket histogram: LDS-privatized counts of dst>>6, one global atomic per
// (block,bucket).
// ===========================================================================
__global__ __launch_bounds__(1024) void bhist_kernel(
    const int* __restrict__ dst, int* __restrict__ bcnt, int nE, int nbuck)
{
    __shared__ int hist[NBMAX];
    const int tid = threadIdx.x;
    const int e0 = blockIdx.x * EPB;
    const int e1 = min(e0 + EPB, nE);

    for (int b = tid; b < nbuck; b += 1024) hist[b] = 0;
    __syncthreads();
    for (int e = e0 + tid; e < e1; e += 1024)
        atomicAdd(&hist[dst[e] >> 6], 1);
    __syncthreads();
    for (int b = tid; b < nbuck; b += 1024) {
        int c = hist[b];
        if (c) atomicAdd(&bcnt[b], c);
    }
}

// single-block exclusive scan of bucket counts -> bbase[nbuck+1], gcur copy;
// also writes rowptr[n] = E.
__global__ __launch_bounds__(1024) void bscan_kernel(
    const int* __restrict__ bcnt, int* __restrict__ bbase,
    int* __restrict__ gcur, int* __restrict__ rowptr, int nbuck, int n, int nE)
{
    __shared__ int tmp[1024];
    __shared__ int carry;
    int t = threadIdx.x;
    if (t == 0) carry = 0;
    __syncthreads();
    for (int c0 = 0; c0 < nbuck; c0 += 1024) {
        int v = (c0 + t < nbuck) ? bcnt[c0 + t] : 0;
        tmp[t] = v;
        __syncthreads();
        for (int off = 1; off < 1024; off <<= 1) {
            int u = (t >= off) ? tmp[t - off] : 0;
            __syncthreads();
            tmp[t] += u;
            __syncthreads();
        }
        int excl = carry + tmp[t] - v;
        if (c0 + t < nbuck) { bbase[c0 + t] = excl; gcur[c0 + t] = excl; }
        __syncthreads();
        if (t == 1023) carry += tmp[1023];
        __syncthreads();
    }
    if (t == 0) { bbase[nbuck] = nE; rowptr[n] = nE; }
}

// ===========================================================================
// coarse bucket scatter with per-(block,bucket) chunk reservation.
// pairs[p] = src | ((dst&63) << 17), grouped by bucket (= dst>>6).
// ===========================================================================
__global__ __launch_bounds__(1024) void coarse_kernel(
    const int* __restrict__ src, const int* __restrict__ dst,
    int* __restrict__ gcur, int* __restrict__ pairs, int nE, int nbuck)
{
    __shared__ int hist[NBMAX];
    const int tid = threadIdx.x;
    const int e0 = blockIdx.x * EPB;
    const int e1 = min(e0 + EPB, nE);

    for (int b = tid; b < nbuck; b += 1024) hist[b] = 0;
    __syncthreads();
    for (int e = e0 + tid; e < e1; e += 1024)
        atomicAdd(&hist[dst[e] >> 6], 1);
    __syncthreads();
    for (int b = tid; b < nbuck; b += 1024) {
        int c = hist[b];
        hist[b] = c ? atomicAdd(&gcur[b], c) : 0;
    }
    __syncthreads();
    for (int e = e0 + tid; e < e1; e += 1024) {
        int d = dst[e];
        int p = atomicAdd(&hist[d >> 6], 1);
        pairs[p] = src[e] | ((d & 63) << 17);
    }
}

// ===========================================================================
// fine pass: one block per bucket. Derives per-node degree / rowptr / invd
// from its private pairs window (no global atomics), then scatters csr.
// ===========================================================================
__global__ __launch_bounds__(256) void fine_kernel(
    const int* __restrict__ pairs, const int* __restrict__ bbase,
    int* __restrict__ rowptr, float* __restrict__ invd,
    int* __restrict__ csr, int n)
{
    __shared__ int cnt[64];
    __shared__ int excl[64];
    __shared__ int cur[64];
    const int tid   = threadIdx.x;
    const int node0 = blockIdx.x * 64;
    const int nn    = min(64, n - node0);
    const int base  = bbase[blockIdx.x];
    const int wend  = bbase[blockIdx.x + 1];

    if (tid < 64) cnt[tid] = 0;
    __syncthreads();
    for (int j = base + tid; j < wend; j += 256)
        atomicAdd(&cnt[pairs[j] >> 17], 1);
    __syncthreads();
    if (tid == 0) {
        int run = 0;
        #pragma unroll
        for (int i = 0; i < 64; ++i) { excl[i] = run; run += cnt[i]; }
    }
    __syncthreads();
    if (tid < nn) {
        int rp = base + excl[tid];
        rowptr[node0 + tid] = rp;
        cur[tid] = rp;
        invd[node0 + tid] = 1.0f / fmaxf((float)cnt[tid], 1.0f);
    }
    __syncthreads();
    for (int j = base + tid; j < wend; j += 256) {
        int e = pairs[j];
        int p = atomicAdd(&cur[e >> 17], 1);
        csr[p] = e & 131071;
    }
}

// ===========================================================================
// fallback path kernels (N > 131072): per-node atomic histogram + scans + fill
// ===========================================================================
__global__ __launch_bounds__(256) void deg_kernel(
    const int* __restrict__ dst, int* __restrict__ deg, int nE)
{
    int e = blockIdx.x * 256 + threadIdx.x;
    if (e < nE) atomicAdd(&deg[dst[e]], 1);
}

__global__ __launch_bounds__(256) void scan1_kernel(
    const int* __restrict__ deg, int* __restrict__ inc,
    int* __restrict__ bsum, int n)
{
    __shared__ int tmp[256];
    int i = blockIdx.x * 256 + threadIdx.x;
    int t = threadIdx.x;
    tmp[t] = (i < n) ? deg[i] : 0;
    __syncthreads();
    for (int off = 1; off < 256; off <<= 1) {
        int v = (t >= off) ? tmp[t - off] : 0;
        __syncthreads();
        tmp[t] += v;
        __syncthreads();
    }
    if (i < n) inc[i] = tmp[t];
    if (t == 255) bsum[blockIdx.x] = tmp[255];
}

__global__ __launch_bounds__(512) void scan2_kernel(int* __restrict__ bsum, int nb)
{
    __shared__ int tmp[512];
    int t = threadIdx.x;
    tmp[t] = (t < nb) ? bsum[t] : 0;
    __syncthreads();
    for (int off = 1; off < 512; off <<= 1) {
        int v = (t >= off) ? tmp[t - off] : 0;
        __syncthreads();
        tmp[t] += v;
        __syncthreads();
    }
    if (t < nb) bsum[t] = (t == 0) ? 0 : tmp[t - 1];
}

__global__ __launch_bounds__(256) void scan3_kernel(
    const int* __restrict__ inc, const int* __restrict__ bsum,
    const int* __restrict__ deg, int* __restrict__ rowptr,
    int* __restrict__ cursor, float* __restrict__ invd, int n)
{
    int i = blockIdx.x * 256 + threadIdx.x;
    if (i > n) return;
    int rp = (i == 0) ? 0 : (inc[i - 1] + bsum[(i - 1) >> 8]);
    rowptr[i] = rp;
    if (i < n) {
        cursor[i] = rp;
        invd[i]   = 1.0f / fmaxf((float)deg[i], 1.0f);
    }
}

__global__ __launch_bounds__(256) void fill_kernel(
    const int* __restrict__ src, const int* __restrict__ dst,
    int* __restrict__ cursor, int* __restrict__ csr, int nE)
{
    int e = blockIdx.x * 256 + threadIdx.x;
    if (e < nE) {
        int pos = atomicAdd(&cursor[dst[e]], 1);
        csr[pos] = src[e];
    }
}

// ===========================================================================
// W permute: Wp[kk(8)][nt(8)][lane(64)][j(8)] = bf16(Wcat[k][c])
// ===========================================================================
__global__ __launch_bounds__(256) void wprep_kernel(
    const float* __restrict__ Wl, const float* __restrict__ Wr,
    unsigned short* __restrict__ Wp)
{
    int t = blockIdx.x * 256 + threadIdx.x;
    if (t >= 4096) return;
    int l  = t & 63;
    int nt = (t >> 6) & 7;
    int kk = t >> 9;
    int c  = nt * 16 + (l & 15);
    int k0 = kk * 32 + (l >> 4) * 8;
    unsigned short o[8];
    #pragma unroll
    for (int j = 0; j < 8; ++j) {
        int k = k0 + j;
        float v = (k < 128) ? Wl[k * 128 + c] : Wr[(k - 128) * 128 + c];
        o[j] = f2b(v);
    }
    uint4 pk;
    pk.x = o[0] | ((unsigned)o[1] << 16);
    pk.y = o[2] | ((unsigned)o[3] << 16);
    pk.z = o[4] | ((unsigned)o[5] << 16);
    pk.w = o[6] | ((unsigned)o[7] << 16);
    *(uint4*)(Wp + (size_t)t * 8) = pk;
}

// ===========================================================================
// gather-aggregate (bf16), 16 lanes/node, 2-deep software pipeline:
// window B's 8 gathers are in flight while window A accumulates.
// csr indices fetched lane-cooperatively (1 coalesced dword / 16 edges)
// and broadcast via __shfl within the 16-lane group.
// ===========================================================================
static __device__ __forceinline__ void acc8(float* a, uint4 v) {
    a[0] += blo(v.x); a[1] += bhi(v.x);
    a[2] += blo(v.y); a[3] += bhi(v.y);
    a[4] += blo(v.z); a[5] += bhi(v.z);
    a[6] += blo(v.w); a[7] += bhi(v.w);
}

__global__ __launch_bounds__(256, 4) void aggb_kernel(
    const unsigned short* __restrict__ Xb, const int* __restrict__ csr,
    const int* __restrict__ rowptr, const float* __restrict__ invd,
    unsigned short* __restrict__ Sb, int n)
{
    const int node = (blockIdx.x * 256 + threadIdx.x) >> 4;
    const int l    = threadIdx.x & 15;
    if (node >= n) return;
    const int beg = rowptr[node];
    const int deg = rowptr[node + 1] - beg;

    unsigned short* qout = Sb + (size_t)node * DD + l * 8;

    if (deg == 0) {
        *(uint4*)qout = make_uint4(0u, 0u, 0u, 0u);
        return;
    }

    const int gb = threadIdx.x & 48;         // 16-lane group base within wave
    const unsigned short* __restrict__ xsl = Xb + l * 8;

    float a[8]  = {0.f,0.f,0.f,0.f,0.f,0.f,0.f,0.f};
    float b8[8] = {0.f,0.f,0.f,0.f,0.f,0.f,0.f,0.f};
    uint4 va[8], vb[8];

    // lane l holds csr[beg + chunkbase + l] (clamped); chunk = 16 edges.
    int cv = csr[beg + min(l, deg - 1)];

#define AGG_ISSUE(buf, jj)                                          \
    {                                                               \
        const int qb = (jj) & 8;                                    \
        _Pragma("unroll")                                           \
        for (int q = 0; q < 8; ++q) {                               \
            int s = __shfl(cv, gb | (qb + q));                      \
            buf[q] = *(const uint4*)(xsl + (size_t)s * DD);         \
        }                                                           \
    }

    AGG_ISSUE(va, 0);                         // prologue: edges [0,8)
    int j = 0;
    for (;;) {
        if (j + 8 >= deg) {                   // tail from va
            int cnt = deg - j;
            #pragma unroll
            for (int q = 0; q < 8; ++q)
                if (q < cnt) acc8((q & 1) ? b8 : a, va[q]);
            break;
        }
        {
            int jj = j + 8;
            if ((jj & 15) == 0) cv = csr[beg + min(jj + l, deg - 1)];
            AGG_ISSUE(vb, jj);
        }
        #pragma unroll
        for (int q = 0; q < 8; ++q) acc8((q & 1) ? b8 : a, va[q]);
        j += 8;
        if (j + 8 >= deg) {                   // tail from vb
            int cnt = deg - j;
            #pragma unroll
            for (int q = 0; q < 8; ++q)
                if (q < cnt) acc8((q & 1) ? b8 : a, vb[q]);
            break;
        }
        {
            int jj = j + 8;
            if ((jj & 15) == 0) cv = csr[beg + min(jj + l, deg - 1)];
            AGG_ISSUE(va, jj);
        }
        #pragma unroll
        for (int q = 0; q < 8; ++q) acc8((q & 1) ? b8 : a, vb[q]);
        j += 8;
    }
#undef AGG_ISSUE

    const float iv = invd[node];
    float r[8];
    #pragma unroll
    for (int i = 0; i < 8; ++i) r[i] = (a[i] + b8[i]) * iv;
    uint4 o;
    o.x = f2b(r[0]) | ((unsigned)f2b(r[1]) << 16);
    o.y = f2b(r[2]) | ((unsigned)f2b(r[3]) << 16);
    o.z = f2b(r[4]) | ((unsigned)f2b(r[5]) << 16);
    o.w = f2b(r[6]) | ((unsigned)f2b(r[7]) << 16);
    *(uint4*)qout = o;
}

// ===========================================================================
// MFMA GEMM + fused bias / L2-normalize / ReLU.
//   norm_relu( Sb[i] @ Wl + bl + Xb[i] @ Wr )  -> Y (fp32) and/or Hb (bf16)
// ===========================================================================
__global__ __launch_bounds__(256) void mmf_kernel(
    const unsigned short* __restrict__ Sb,
    const unsigned short* Xb,            // may alias Hb
    const unsigned short* __restrict__ Wp,
    const float* __restrict__ bl,
    float* __restrict__ Y,
    unsigned short* Hb,
    int n, int writeY, int writeH)
{
    const int wid  = threadIdx.x >> 6;
    const int l    = threadIdx.x & 63;
    const int row0 = blockIdx.x * 64 + wid * 16;
    const int lr   = l & 15;
    const int lk   = l >> 4;

    int arow = row0 + lr;
    if (arow >= n) arow = n - 1;
    const size_t abase = (size_t)arow * DD + lk * 8;

    f32x4 acc[8];
    #pragma unroll
    for (int t = 0; t < 8; ++t) acc[t] = (f32x4){0.f, 0.f, 0.f, 0.f};

    const bf16x8* wp = (const bf16x8*)Wp + l;

    #pragma unroll
    for (int kk = 0; kk < 8; ++kk) {
        bf16x8 afrag = (kk < 4)
            ? *(const bf16x8*)(Sb + abase + kk * 32)
            : *(const bf16x8*)(Xb + abase + (kk - 4) * 32);
        #pragma unroll
        for (int t = 0; t < 8; ++t) {
            bf16x8 bfrag = wp[(kk * 8 + t) * 64];
            acc[t] = __builtin_amdgcn_mfma_f32_16x16x32_bf16(afrag, bfrag, acc[t], 0, 0, 0);
        }
    }

    float bv[8];
    #pragma unroll
    for (int t = 0; t < 8; ++t) bv[t] = bl[t * 16 + lr];

    #pragma unroll
    for (int j = 0; j < 4; ++j) {
        float ss = 0.f;
        #pragma unroll
        for (int t = 0; t < 8; ++t) {
            acc[t][j] += bv[t];
            ss += acc[t][j] * acc[t][j];
        }
        ss += __shfl_xor(ss, 1);
        ss += __shfl_xor(ss, 2);
        ss += __shfl_xor(ss, 4);
        ss += __shfl_xor(ss, 8);
        float sc = 1.0f / fmaxf(sqrtf(ss), 1e-12f);

        int g = row0 + lk * 4 + j;
        if (g < n) {
            #pragma unroll
            for (int t = 0; t < 8; ++t) {
                float o = fmaxf(acc[t][j] * sc, 0.f);
                if (writeY) Y[(size_t)g * DD + t * 16 + lr] = o;
                if (writeH) Hb[(size_t)g * DD + t * 16 + lr] = f2b(o);
            }
        }
    }
}

// ===========================================================================
extern "C" void kernel_launch(void* const* d_in, const int* in_sizes, int n_in,
                              void* d_out, int out_size, void* d_ws, size_t ws_size,
                              hipStream_t stream)
{
    const float* x   = (const float*)d_in[0];
    const int*   ei  = (const int*)d_in[1];
    const float* Wl1 = (const float*)d_in[2];
    const float* bl1 = (const float*)d_in[3];
    const float* Wr1 = (const float*)d_in[4];
    const float* Wl2 = (const float*)d_in[5];
    const float* bl2 = (const float*)d_in[6];
    const float* Wr2 = (const float*)d_in[7];
    float* out = (float*)d_out;

    const int N = in_sizes[0] / DD;
    const int E = in_sizes[1] / 2;
    const int* src = ei;
    const int* dst = ei + E;

    // ---- workspace layout --------------------------------------------------
    char* w = (char*)d_ws;
    size_t off = 0;
    auto alloc = [&](size_t bytes) {
        void* p = w + off;
        off += (bytes + 255) & ~(size_t)255;
        return p;
    };
    unsigned short* xb   = (unsigned short*)alloc((size_t)N * DD * 2);  // also Hb
    unsigned short* Sb   = (unsigned short*)alloc((size_t)N * DD * 2);
    int*   csr    = (int*)  alloc((size_t)E * sizeof(int));
    int*   deg    = (int*)  alloc((size_t)N * sizeof(int));
    int*   inc    = (int*)  alloc((size_t)N * sizeof(int));
    int*   rowptr = (int*)  alloc((size_t)(N + 1) * sizeof(int));
    int*   cursor = (int*)  alloc((size_t)N * sizeof(int));
    float* invd   = (float*)alloc((size_t)N * sizeof(float));
    int*   bsum   = (int*)  alloc(512 * sizeof(int));
    unsigned short* Wp1 = (unsigned short*)alloc(4096 * 8 * 2);
    unsigned short* Wp2 = (unsigned short*)alloc(4096 * 8 * 2);
    int*   gcur   = (int*)  alloc(NBMAX * sizeof(int));
    int*   bcnt   = (int*)  alloc(NBMAX * sizeof(int));
    int*   bbase  = (int*)  alloc((NBMAX + 1) * sizeof(int));
    int*   pairs  = (int*)Sb;            // alias: Sb not live during CSR build
    (void)ws_size;

    const int nbuck = (N + 63) / 64;
    const int nebl  = (E + EPB - 1) / EPB;

    cvt_kernel<<<(N * DD / 8 + 255) / 256, 256, 0, stream>>>(x, xb, N * DD / 8);

    if (N <= 131072 && nbuck <= NBMAX) {
        // ---- atomic-light CSR build ----------------------------------------
        hipMemsetAsync(bcnt, 0, (size_t)nbuck * sizeof(int), stream);
        bhist_kernel <<<nebl, 1024, 0, stream>>>(dst, bcnt, E, nbuck);
        bscan_kernel <<<1, 1024, 0, stream>>>(bcnt, bbase, gcur, rowptr, nbuck, N, E);
        coarse_kernel<<<nebl, 1024, 0, stream>>>(src, dst, gcur, pairs, E, nbuck);
        fine_kernel  <<<nbuck, 256, 0, stream>>>(pairs, bbase, rowptr, invd, csr, N);
    } else {
        // ---- fallback: per-node atomic histogram + scans + fill ------------
        const int nb = (N + 255) / 256;
        hipMemsetAsync(deg, 0, (size_t)N * sizeof(int), stream);
        deg_kernel  <<<(E + 255) / 256, 256, 0, stream>>>(dst, deg, E);
        scan1_kernel<<<nb, 256, 0, stream>>>(deg, inc, bsum, N);
        scan2_kernel<<<1, 512, 0, stream>>>(bsum, nb);
        scan3_kernel<<<(N + 256) / 256, 256, 0, stream>>>(inc, bsum, deg,
                                                          rowptr, cursor, invd, N);
        fill_kernel <<<(E + 255) / 256, 256, 0, stream>>>(src, dst, cursor, csr, E);
    }
    wprep_kernel<<<16, 256, 0, stream>>>(Wl1, Wr1, Wp1);
    wprep_kernel<<<16, 256, 0, stream>>>(Wl2, Wr2, Wp2);

    const int aggGrid = (N * 16 + 255) / 256;
    const int mmGrid  = (N + 63) / 64;

    // ---- layer 1: hb(xb) = bf16(norm_relu([agg(xb)|xb] @ Wp1 + bl1)) -------
    aggb_kernel<<<aggGrid, 256, 0, stream>>>(xb, csr, rowptr, invd, Sb, N);
    mmf_kernel <<<mmGrid, 256, 0, stream>>>(Sb, xb, Wp1, bl1, out, xb, N, 0, 1);

    // ---- layer 2: out = norm_relu([agg(hb)|hb] @ Wp2 + bl2) ----------------
    aggb_kernel<<<aggGrid, 256, 0, stream>>>(xb, csr, rowptr, invd, Sb, N);
    mmf_kernel <<<mmGrid, 256, 0, stream>>>(Sb, xb, Wp2, bl2, out, xb, N, 1, 0);
}

// Round 7
// 218.508 us; speedup vs baseline: 26.5494x; 1.0808x over previous
//
#include <hip/hip_runtime.h>

#define DD 128
#define NBMAX 2048          // max coarse buckets (supports N <= 131072)
#define EPB 16384           // edges per coarse block

typedef short bf16x8 __attribute__((ext_vector_type(8)));
typedef float f32x4  __attribute__((ext_vector_type(4)));

// ---- bf16 helpers (RNE) ----------------------------------------------------
static __device__ __forceinline__ unsigned short f2b(float f) {
    union { float f; unsigned u; } v; v.f = f;
    unsigned u = v.u;
    return (unsigned short)((u + 0x7FFFu + ((u >> 16) & 1u)) >> 16);
}
static __device__ __forceinline__ float blo(unsigned p) {
    union { unsigned u; float f; } v; v.u = p << 16; return v.f;
}
static __device__ __forceinline__ float bhi(unsigned p) {
    union { unsigned u; float f; } v; v.u = p & 0xFFFF0000u; return v.f;
}

// ===========================================================================
// x (fp32) -> xb (bf16), 8 elems/thread
// ===========================================================================
__global__ __launch_bounds__(256) void cvt_kernel(
    const float* __restrict__ X, unsigned short* __restrict__ Xb, int n8)
{
    int i = blockIdx.x * 256 + threadIdx.x;
    if (i >= n8) return;
    const float4* p = (const float4*)(X + (size_t)i * 8);
    float4 a = p[0], b = p[1];
    uint4 o;
    o.x = f2b(a.x) | ((unsigned)f2b(a.y) << 16);
    o.y = f2b(a.z) | ((unsigned)f2b(a.w) << 16);
    o.z = f2b(b.x) | ((unsigned)f2b(b.y) << 16);
    o.w = f2b(b.z) | ((unsigned)f2b(b.w) << 16);
    *(uint4*)(Xb + (size_t)i * 8) = o;
}

// ===========================================================================
// bucket histogram: LDS-privatized counts of dst>>6
// ===========================================================================
__global__ __launch_bounds__(1024) void bhist_kernel(
    const int* __restrict__ dst, int* __restrict__ bcnt, int nE, int nbuck)
{
    __shared__ int hist[NBMAX];
    const int tid = threadIdx.x;
    const int e0 = blockIdx.x * EPB;
    const int e1 = min(e0 + EPB, nE);

    for (int b = tid; b < nbuck; b += 1024) hist[b] = 0;
    __syncthreads();
    for (int e = e0 + tid; e < e1; e += 1024)
        atomicAdd(&hist[dst[e] >> 6], 1);
    __syncthreads();
    for (int b = tid; b < nbuck; b += 1024) {
        int c = hist[b];
        if (c) atomicAdd(&bcnt[b], c);
    }
}

// single-block exclusive scan of bucket counts -> bbase[nbuck+1], gcur copy;
// also writes rowptr[n] = E.
__global__ __launch_bounds__(1024) void bscan_kernel(
    const int* __restrict__ bcnt, int* __restrict__ bbase,
    int* __restrict__ gcur, int* __restrict__ rowptr, int nbuck, int n, int nE)
{
    __shared__ int tmp[1024];
    __shared__ int carry;
    int t = threadIdx.x;
    if (t == 0) carry = 0;
    __syncthreads();
    for (int c0 = 0; c0 < nbuck; c0 += 1024) {
        int v = (c0 + t < nbuck) ? bcnt[c0 + t] : 0;
        tmp[t] = v;
        __syncthreads();
        for (int off = 1; off < 1024; off <<= 1) {
            int u = (t >= off) ? tmp[t - off] : 0;
            __syncthreads();
            tmp[t] += u;
            __syncthreads();
        }
        int excl = carry + tmp[t] - v;
        if (c0 + t < nbuck) { bbase[c0 + t] = excl; gcur[c0 + t] = excl; }
        __syncthreads();
        if (t == 1023) carry += tmp[1023];
        __syncthreads();
    }
    if (t == 0) { bbase[nbuck] = nE; rowptr[n] = nE; }
}

// ===========================================================================
// coarse bucket scatter with per-(block,bucket) chunk reservation.
// pairs[p] = src | ((dst&63) << 17), grouped by bucket (= dst>>6).
// ===========================================================================
__global__ __launch_bounds__(1024) void coarse_kernel(
    const int* __restrict__ src, const int* __restrict__ dst,
    int* __restrict__ gcur, int* __restrict__ pairs, int nE, int nbuck)
{
    __shared__ int hist[NBMAX];
    const int tid = threadIdx.x;
    const int e0 = blockIdx.x * EPB;
    const int e1 = min(e0 + EPB, nE);

    for (int b = tid; b < nbuck; b += 1024) hist[b] = 0;
    __syncthreads();
    for (int e = e0 + tid; e < e1; e += 1024)
        atomicAdd(&hist[dst[e] >> 6], 1);
    __syncthreads();
    for (int b = tid; b < nbuck; b += 1024) {
        int c = hist[b];
        hist[b] = c ? atomicAdd(&gcur[b], c) : 0;
    }
    __syncthreads();
    for (int e = e0 + tid; e < e1; e += 1024) {
        int d = dst[e];
        int p = atomicAdd(&hist[d >> 6], 1);
        pairs[p] = src[e] | ((d & 63) << 17);
    }
}

// ===========================================================================
// fine pass: one block per bucket. Derives per-node degree / rowptr from its
// private pairs window (no global atomics), then scatters csr.
// ===========================================================================
__global__ __launch_bounds__(256) void fine_kernel(
    const int* __restrict__ pairs, const int* __restrict__ bbase,
    int* __restrict__ rowptr, int* __restrict__ csr, int n)
{
    __shared__ int cnt[64];
    __shared__ int excl[64];
    __shared__ int cur[64];
    const int tid   = threadIdx.x;
    const int node0 = blockIdx.x * 64;
    const int nn    = min(64, n - node0);
    const int base  = bbase[blockIdx.x];
    const int wend  = bbase[blockIdx.x + 1];

    if (tid < 64) cnt[tid] = 0;
    __syncthreads();
    for (int j = base + tid; j < wend; j += 256)
        atomicAdd(&cnt[pairs[j] >> 17], 1);
    __syncthreads();
    if (tid == 0) {
        int run = 0;
        #pragma unroll
        for (int i = 0; i < 64; ++i) { excl[i] = run; run += cnt[i]; }
    }
    __syncthreads();
    if (tid < nn) {
        int rp = base + excl[tid];
        rowptr[node0 + tid] = rp;
        cur[tid] = rp;
    }
    __syncthreads();
    for (int j = base + tid; j < wend; j += 256) {
        int e = pairs[j];
        int p = atomicAdd(&cur[e >> 17], 1);
        csr[p] = e & 131071;
    }
}

// ===========================================================================
// fallback path kernels (N > 131072): per-node atomic histogram + scans + fill
// ===========================================================================
__global__ __launch_bounds__(256) void deg_kernel(
    const int* __restrict__ dst, int* __restrict__ deg, int nE)
{
    int e = blockIdx.x * 256 + threadIdx.x;
    if (e < nE) atomicAdd(&deg[dst[e]], 1);
}

__global__ __launch_bounds__(256) void scan1_kernel(
    const int* __restrict__ deg, int* __restrict__ inc,
    int* __restrict__ bsum, int n)
{
    __shared__ int tmp[256];
    int i = blockIdx.x * 256 + threadIdx.x;
    int t = threadIdx.x;
    tmp[t] = (i < n) ? deg[i] : 0;
    __syncthreads();
    for (int off = 1; off < 256; off <<= 1) {
        int v = (t >= off) ? tmp[t - off] : 0;
        __syncthreads();
        tmp[t] += v;
        __syncthreads();
    }
    if (i < n) inc[i] = tmp[t];
    if (t == 255) bsum[blockIdx.x] = tmp[255];
}

__global__ __launch_bounds__(512) void scan2_kernel(int* __restrict__ bsum, int nb)
{
    __shared__ int tmp[512];
    int t = threadIdx.x;
    tmp[t] = (t < nb) ? bsum[t] : 0;
    __syncthreads();
    for (int off = 1; off < 512; off <<= 1) {
        int v = (t >= off) ? tmp[t - off] : 0;
        __syncthreads();
        tmp[t] += v;
        __syncthreads();
    }
    if (t < nb) bsum[t] = (t == 0) ? 0 : tmp[t - 1];
}

__global__ __launch_bounds__(256) void scan3_kernel(
    const int* __restrict__ inc, const int* __restrict__ bsum,
    int* __restrict__ rowptr, int* __restrict__ cursor, int n)
{
    int i = blockIdx.x * 256 + threadIdx.x;
    if (i > n) return;
    int rp = (i == 0) ? 0 : (inc[i - 1] + bsum[(i - 1) >> 8]);
    rowptr[i] = rp;
    if (i < n) cursor[i] = rp;
}

__global__ __launch_bounds__(256) void fill_kernel(
    const int* __restrict__ src, const int* __restrict__ dst,
    int* __restrict__ cursor, int* __restrict__ csr, int nE)
{
    int e = blockIdx.x * 256 + threadIdx.x;
    if (e < nE) {
        int pos = atomicAdd(&cursor[dst[e]], 1);
        csr[pos] = src[e];
    }
}

// ===========================================================================
// W permute: Wp[kk(8)][nt(8)][lane(64)][j(8)] = bf16(Wcat[k][c])
// ===========================================================================
__global__ __launch_bounds__(256) void wprep_kernel(
    const float* __restrict__ Wl, const float* __restrict__ Wr,
    unsigned short* __restrict__ Wp)
{
    int t = blockIdx.x * 256 + threadIdx.x;
    if (t >= 4096) return;
    int l  = t & 63;
    int nt = (t >> 6) & 7;
    int kk = t >> 9;
    int c  = nt * 16 + (l & 15);
    int k0 = kk * 32 + (l >> 4) * 8;
    unsigned short o[8];
    #pragma unroll
    for (int j = 0; j < 8; ++j) {
        int k = k0 + j;
        float v = (k < 128) ? Wl[k * 128 + c] : Wr[(k - 128) * 128 + c];
        o[j] = f2b(v);
    }
    uint4 pk;
    pk.x = o[0] | ((unsigned)o[1] << 16);
    pk.y = o[2] | ((unsigned)o[3] << 16);
    pk.z = o[4] | ((unsigned)o[5] << 16);
    pk.w = o[6] | ((unsigned)o[7] << 16);
    *(uint4*)(Wp + (size_t)t * 8) = pk;
}

// ===========================================================================
// FUSED: gather-aggregate (into swizzled LDS tile) + MFMA GEMM + fused
// bias / L2-normalize / ReLU epilogue.
//   out[i] = norm_relu( mean_nbr(Xb)[i] @ Wl + bl + Xb[i] @ Wr )
// Block = 256 threads handles a 64-node tile.
// Phase 1: 16 lanes/node, 4 nodes/group-round, 2-deep pipelined gather,
//          fp32 accumulate, mean -> bf16 row in LDS (chunk ^= row&15 swizzle).
// Phase 2: 4 waves x (16 rows x 128 cols) MFMA; A kk<4 from LDS, kk>=4 from Xb.
// Hb must NOT alias Xb (concurrent blocks still gather from Xb).
// ===========================================================================
static __device__ __forceinline__ void acc8(float* a, uint4 v) {
    a[0] += blo(v.x); a[1] += bhi(v.x);
    a[2] += blo(v.y); a[3] += bhi(v.y);
    a[4] += blo(v.z); a[5] += bhi(v.z);
    a[6] += blo(v.w); a[7] += bhi(v.w);
}

__global__ __launch_bounds__(256, 4) void fused_kernel(
    const unsigned short* __restrict__ Xb,
    const int* __restrict__ csr,
    const int* __restrict__ rowptr,
    const unsigned short* __restrict__ Wp,
    const float* __restrict__ bl,
    float* __restrict__ Y,
    unsigned short* __restrict__ Hb,
    int n, int writeY, int writeH)
{
    __shared__ unsigned short Slds[64 * DD];     // 16 KB bf16 agg tile

    const int tid  = threadIdx.x;
    const int row0 = blockIdx.x * 64;
    const int l    = tid & 15;                   // lane within 16-lane group
    const int grp  = tid >> 4;                   // 0..15
    const int gb   = tid & 48;                   // group base within wave
    const unsigned short* __restrict__ xsl = Xb + l * 8;

    // -------------------- phase 1: gather 4 nodes per group -----------------
    for (int round = 0; round < 4; ++round) {
        const int nl   = grp + 16 * round;       // local row 0..63
        const int node = row0 + nl;
        if (node < n) {
            const int beg = rowptr[node];
            const int deg = rowptr[node + 1] - beg;
            uint4 o;
            if (deg == 0) {
                o = make_uint4(0u, 0u, 0u, 0u);
            } else {
                float a[8]  = {0.f,0.f,0.f,0.f,0.f,0.f,0.f,0.f};
                float b8[8] = {0.f,0.f,0.f,0.f,0.f,0.f,0.f,0.f};
                uint4 va[8], vb[8];
                int cv = csr[beg + min(l, deg - 1)];

#define AGG_ISSUE(buf, jj)                                          \
    {                                                               \
        const int qb = (jj) & 8;                                    \
        _Pragma("unroll")                                           \
        for (int q = 0; q < 8; ++q) {                               \
            int s = __shfl(cv, gb | (qb + q));                      \
            buf[q] = *(const uint4*)(xsl + (size_t)s * DD);         \
        }                                                           \
    }
                AGG_ISSUE(va, 0);
                int j = 0;
                for (;;) {
                    if (j + 8 >= deg) {
                        int cnt = deg - j;
                        #pragma unroll
                        for (int q = 0; q < 8; ++q)
                            if (q < cnt) acc8((q & 1) ? b8 : a, va[q]);
                        break;
                    }
                    {
                        int jj = j + 8;
                        if ((jj & 15) == 0) cv = csr[beg + min(jj + l, deg - 1)];
                        AGG_ISSUE(vb, jj);
                    }
                    #pragma unroll
                    for (int q = 0; q < 8; ++q) acc8((q & 1) ? b8 : a, va[q]);
                    j += 8;
                    if (j + 8 >= deg) {
                        int cnt = deg - j;
                        #pragma unroll
                        for (int q = 0; q < 8; ++q)
                            if (q < cnt) acc8((q & 1) ? b8 : a, vb[q]);
                        break;
                    }
                    {
                        int jj = j + 8;
                        if ((jj & 15) == 0) cv = csr[beg + min(jj + l, deg - 1)];
                        AGG_ISSUE(va, jj);
                    }
                    #pragma unroll
                    for (int q = 0; q < 8; ++q) acc8((q & 1) ? b8 : a, vb[q]);
                    j += 8;
                }
#undef AGG_ISSUE
                const float iv = 1.0f / (float)deg;
                float r[8];
                #pragma unroll
                for (int i = 0; i < 8; ++i) r[i] = (a[i] + b8[i]) * iv;
                o.x = f2b(r[0]) | ((unsigned)f2b(r[1]) << 16);
                o.y = f2b(r[2]) | ((unsigned)f2b(r[3]) << 16);
                o.z = f2b(r[4]) | ((unsigned)f2b(r[5]) << 16);
                o.w = f2b(r[6]) | ((unsigned)f2b(r[7]) << 16);
            }
            // swizzled store: chunk l of row nl -> slot l ^ (nl & 15)
            *(uint4*)(Slds + nl * DD + ((l ^ (nl & 15)) << 3)) = o;
        }
    }
    __syncthreads();

    // -------------------- phase 2: MFMA + fused epilogue --------------------
    const int wid = tid >> 6;
    const int l64 = tid & 63;
    const int lr  = l64 & 15;                    // A row in tile / C col
    const int lk  = l64 >> 4;                    // k-chunk (0..3)
    const int r   = wid * 16 + lr;               // tile row (0..63)

    int arow = row0 + r;
    if (arow >= n) arow = n - 1;                 // clamp loads; stores guarded
    const size_t abase = (size_t)arow * DD + lk * 8;

    f32x4 acc[8];
    #pragma unroll
    for (int t = 0; t < 8; ++t) acc[t] = (f32x4){0.f, 0.f, 0.f, 0.f};

    const bf16x8* wp = (const bf16x8*)Wp + l64;

    #pragma unroll
    for (int kk = 0; kk < 8; ++kk) {
        bf16x8 afrag;
        if (kk < 4) {
            const int c = kk * 4 + lk;           // chunk within row
            afrag = *(const bf16x8*)(Slds + r * DD + (((c ^ lr)) << 3));
        } else {
            afrag = *(const bf16x8*)(Xb + abase + (kk - 4) * 32);
        }
        #pragma unroll
        for (int t = 0; t < 8; ++t) {
            bf16x8 bfrag = wp[(kk * 8 + t) * 64];
            acc[t] = __builtin_amdgcn_mfma_f32_16x16x32_bf16(afrag, bfrag, acc[t], 0, 0, 0);
        }
    }

    float bv[8];
    #pragma unroll
    for (int t = 0; t < 8; ++t) bv[t] = bl[t * 16 + lr];

    #pragma unroll
    for (int j = 0; j < 4; ++j) {
        float ss = 0.f;
        #pragma unroll
        for (int t = 0; t < 8; ++t) {
            acc[t][j] += bv[t];
            ss += acc[t][j] * acc[t][j];
        }
        ss += __shfl_xor(ss, 1);
        ss += __shfl_xor(ss, 2);
        ss += __shfl_xor(ss, 4);
        ss += __shfl_xor(ss, 8);
        float sc = 1.0f / fmaxf(sqrtf(ss), 1e-12f);

        int g = row0 + wid * 16 + lk * 4 + j;
        if (g < n) {
            #pragma unroll
            for (int t = 0; t < 8; ++t) {
                float o = fmaxf(acc[t][j] * sc, 0.f);
                if (writeY) Y[(size_t)g * DD + t * 16 + lr] = o;
                if (writeH) Hb[(size_t)g * DD + t * 16 + lr] = f2b(o);
            }
        }
    }
}

// ===========================================================================
extern "C" void kernel_launch(void* const* d_in, const int* in_sizes, int n_in,
                              void* d_out, int out_size, void* d_ws, size_t ws_size,
                              hipStream_t stream)
{
    const float* x   = (const float*)d_in[0];
    const int*   ei  = (const int*)d_in[1];
    const float* Wl1 = (const float*)d_in[2];
    const float* bl1 = (const float*)d_in[3];
    const float* Wr1 = (const float*)d_in[4];
    const float* Wl2 = (const float*)d_in[5];
    const float* bl2 = (const float*)d_in[6];
    const float* Wr2 = (const float*)d_in[7];
    float* out = (float*)d_out;

    const int N = in_sizes[0] / DD;
    const int E = in_sizes[1] / 2;
    const int* src = ei;
    const int* dst = ei + E;

    // ---- workspace layout --------------------------------------------------
    char* w = (char*)d_ws;
    size_t off = 0;
    auto alloc = [&](size_t bytes) {
        void* p = w + off;
        off += (bytes + 255) & ~(size_t)255;
        return p;
    };
    unsigned short* xb  = (unsigned short*)alloc((size_t)N * DD * 2);
    unsigned short* hb  = (unsigned short*)alloc((size_t)N * DD * 2);  // h1 bf16; pairs alias
    int*   csr    = (int*)  alloc((size_t)E * sizeof(int));
    int*   deg    = (int*)  alloc((size_t)N * sizeof(int));
    int*   inc    = (int*)  alloc((size_t)N * sizeof(int));
    int*   rowptr = (int*)  alloc((size_t)(N + 1) * sizeof(int));
    int*   cursor = (int*)  alloc((size_t)N * sizeof(int));
    int*   bsum   = (int*)  alloc(512 * sizeof(int));
    unsigned short* Wp1 = (unsigned short*)alloc(4096 * 8 * 2);
    unsigned short* Wp2 = (unsigned short*)alloc(4096 * 8 * 2);
    int*   gcur   = (int*)  alloc(NBMAX * sizeof(int));
    int*   bcnt   = (int*)  alloc(NBMAX * sizeof(int));
    int*   bbase  = (int*)  alloc((NBMAX + 1) * sizeof(int));
    int*   pairs  = (int*)hb;            // alias: hb not live during CSR build
    (void)ws_size;

    const int nbuck = (N + 63) / 64;
    const int nebl  = (E + EPB - 1) / EPB;

    cvt_kernel<<<(N * DD / 8 + 255) / 256, 256, 0, stream>>>(x, xb, N * DD / 8);

    if (N <= 131072 && nbuck <= NBMAX) {
        // ---- atomic-light CSR build ----------------------------------------
        hipMemsetAsync(bcnt, 0, (size_t)nbuck * sizeof(int), stream);
        bhist_kernel <<<nebl, 1024, 0, stream>>>(dst, bcnt, E, nbuck);
        bscan_kernel <<<1, 1024, 0, stream>>>(bcnt, bbase, gcur, rowptr, nbuck, N, E);
        coarse_kernel<<<nebl, 1024, 0, stream>>>(src, dst, gcur, pairs, E, nbuck);
        fine_kernel  <<<nbuck, 256, 0, stream>>>(pairs, bbase, rowptr, csr, N);
    } else {
        // ---- fallback: per-node atomic histogram + scans + fill ------------
        const int nb = (N + 255) / 256;
        hipMemsetAsync(deg, 0, (size_t)N * sizeof(int), stream);
        deg_kernel  <<<(E + 255) / 256, 256, 0, stream>>>(dst, deg, E);
        scan1_kernel<<<nb, 256, 0, stream>>>(deg, inc, bsum, N);
        scan2_kernel<<<1, 512, 0, stream>>>(bsum, nb);
        scan3_kernel<<<(N + 256) / 256, 256, 0, stream>>>(inc, bsum, rowptr, cursor, N);
        fill_kernel <<<(E + 255) / 256, 256, 0, stream>>>(src, dst, cursor, csr, E);
    }
    wprep_kernel<<<16, 256, 0, stream>>>(Wl1, Wr1, Wp1);
    wprep_kernel<<<16, 256, 0, stream>>>(Wl2, Wr2, Wp2);

    const int grid = (N + 63) / 64;

    // ---- layer 1: hb = bf16(norm_relu([agg(xb)|xb] @ Wp1 + bl1)) -----------
    fused_kernel<<<grid, 256, 0, stream>>>(xb, csr, rowptr, Wp1, bl1,
                                           out, hb, N, 0, 1);
    // ---- layer 2: out = norm_relu([agg(hb)|hb] @ Wp2 + bl2) ----------------
    fused_kernel<<<grid, 256, 0, stream>>>(hb, csr, rowptr, Wp2, bl2,
                                           out, nullptr, N, 1, 0);
}